// Round 2
// baseline (1139.753 us; speedup 1.0000x reference)
//
#include <hip/hip_runtime.h>
#include <cstdint>
#include <cstddef>

typedef unsigned short u16;
typedef __attribute__((ext_vector_type(8))) __bf16 bf16x8;
typedef __attribute__((ext_vector_type(4))) float f32x4;

typedef __attribute__((address_space(1))) const void GAS;
typedef __attribute__((address_space(3))) void LAS;

__device__ __forceinline__ void gld_lds16(const void* g, void* l) {
  __builtin_amdgcn_global_load_lds((GAS*)g, (LAS*)l, 16, 0, 0);
}

__device__ __forceinline__ u16 f2bf(float f) {
  union { float f; unsigned u; } x; x.f = f;
  unsigned r = x.u + 0x7FFFu + ((x.u >> 16) & 1u);
  return (u16)(r >> 16);
}
__device__ __forceinline__ float bf2f(u16 s) {
  union { unsigned u; float f; } x; x.u = ((unsigned)s) << 16;
  return x.f;
}
__device__ __forceinline__ f32x4 mfma16(bf16x8 a, bf16x8 b, f32x4 c) {
  return __builtin_amdgcn_mfma_f32_16x16x32_bf16(a, b, c, 0, 0, 0);
}

// ---------------- small prep kernels ----------------

__global__ void selmap_k(const int* __restrict__ nzb, int* __restrict__ map) {
  int t = threadIdx.x;            // 1024 threads
  map[t] = -1;
  __syncthreads();
  if (t < 512) map[nzb[t]] = t;
}

__global__ __launch_bounds__(256) void castw_k(const float* __restrict__ in,
                                               u16* __restrict__ out, int n4) {
  int i = blockIdx.x * 256 + threadIdx.x;
  if (i >= n4) return;
  float4 v = ((const float4*)in)[i];
  u16 o[4] = {f2bf(v.x), f2bf(v.y), f2bf(v.z), f2bf(v.w)};
  ((uint2*)out)[i] = *(uint2*)o;
}

__global__ __launch_bounds__(256) void adaln_k(const float* __restrict__ c,
    const float* __restrict__ w, const float* __restrict__ b, float* __restrict__ mods) {
  int j = blockIdx.x * 256 + threadIdx.x;  // 0..3071
  int bt = blockIdx.y;
  const float4* cr = (const float4*)(c + bt * 512);
  const float4* wr = (const float4*)(w + (size_t)j * 512);
  float s = 0.f;
  #pragma unroll 4
  for (int k = 0; k < 128; ++k) {
    float4 a = wr[k], q = cr[k];
    s += a.x * q.x + a.y * q.y + a.z * q.z + a.w * q.w;
  }
  mods[bt * 3072 + j] = s + b[j];
}

// rope the shared empty-block K, copy/transpose empty V
__global__ __launch_bounds__(256) void kvempty_k(const float* __restrict__ kve,
    const float* __restrict__ cT, const float* __restrict__ sT,
    u16* __restrict__ kempty, u16* __restrict__ vTempty) {
  int T = blockIdx.x * 256 + threadIdx.x;  // 32768
  int h = T >> 12, p = (T >> 6) & 63, d = T & 63;
  float kv = kve[p * 1024 + h * 64 + d];
  float pv = kve[p * 1024 + h * 64 + (d ^ 32)];
  float cs = cT[p * 64 + d], sn = sT[p * 64 + d];
  float r = kv * cs + ((d < 32) ? -pv : pv) * sn;
  kempty[(h * 64 + p) * 64 + d] = f2bf(r);
  vTempty[(h * 64 + d) * 64 + p] = f2bf(kve[p * 1024 + 512 + h * 64 + d]);
}

// ---------------- LN1 + modulate + block-gather (selected rows only) ----------------

__global__ __launch_bounds__(256) void ln1_k(const float* __restrict__ x,
    const float* __restrict__ nw, const float* __restrict__ mods,
    const int* __restrict__ nzb, u16* __restrict__ xm) {
  int row = blockIdx.x * 4 + (threadIdx.x >> 6);  // 0..32767 (sel*64 + p)
  int t = threadIdx.x & 63;
  int sel = row >> 6, p = row & 63;
  int g = nzb[sel];
  int bt = g >> 9, blk = g & 511;
  int s = (blk >> 6) * 4096 + (p >> 4) * 1024 + ((blk >> 3) & 7) * 128
        + ((p >> 2) & 3) * 32 + (blk & 7) * 4 + (p & 3);
  const float* src = x + ((size_t)bt * 32768 + s) * 512;
  int d0 = t * 8;
  float4 a = *(const float4*)(src + d0);
  float4 b = *(const float4*)(src + d0 + 4);
  float v[8] = {a.x, a.y, a.z, a.w, b.x, b.y, b.z, b.w};
  float sum = 0.f, sq = 0.f;
  #pragma unroll
  for (int j = 0; j < 8; ++j) { sum += v[j]; sq += v[j] * v[j]; }
  #pragma unroll
  for (int m = 1; m < 64; m <<= 1) {
    sum += __shfl_xor(sum, m, 64);
    sq  += __shfl_xor(sq, m, 64);
  }
  float mean = sum * (1.f / 512.f);
  float var = sq * (1.f / 512.f) - mean * mean;
  float rstd = rsqrtf(var + 1e-5f);
  const float* mb = mods + bt * 3072;
  u16 o[8];
  #pragma unroll
  for (int j = 0; j < 8; ++j) {
    int d = d0 + j;
    float xn = (v[j] - mean) * rstd * nw[d];
    o[j] = f2bf(xn * (1.f + mb[512 + d]) + mb[d]);
  }
  *(uint4*)(xm + (size_t)row * 512 + d0) = *(uint4*)o;
}

// ---------------- generic bf16 GEMM  C = A @ W^T  (M,N,K % 128,128,32 == 0) ----------------
// EPI: 0 = store bf16; 1 = store f32; 2 = +bias, gelu, store bf16;
//      3 = +bias, out[grow] = x1[grow] + gate_mlp*val (final output)

template <int EPI>
__global__ __launch_bounds__(256) void gemm_bt(const u16* __restrict__ A,
    const u16* __restrict__ W, int M, int N, int K, void* __restrict__ outp,
    const float* __restrict__ bias, const float* __restrict__ x1,
    const float* __restrict__ mods, int rowOff) {
  __shared__ u16 lA[128 * 32];
  __shared__ u16 lB[128 * 32];
  const int bm = blockIdx.x * 128, bn = blockIdx.y * 128;
  const int tid = threadIdx.x;
  const int w = tid >> 6, l = tid & 63;
  const int lr = l & 15, lg = l >> 4;
  const int wr = w >> 1, wc = w & 1;
  f32x4 acc[4][4];
  #pragma unroll
  for (int i = 0; i < 4; ++i)
    #pragma unroll
    for (int j = 0; j < 4; ++j) acc[i][j] = (f32x4){0.f, 0.f, 0.f, 0.f};
  const int nk = K >> 5;
  const int arow = l >> 2;          // 0..15 in chunk
  const int acol = (l & 3) * 8;
  for (int ks = 0; ks < nk; ++ks) {
    __syncthreads();
    #pragma unroll
    for (int cc = 0; cc < 2; ++cc) {
      int ch = w * 2 + cc;
      const u16* ga = A + (size_t)(bm + ch * 16 + arow) * K + ks * 32 + acol;
      gld_lds16(ga, lA + ch * 512);
      const u16* gb = W + (size_t)(bn + ch * 16 + arow) * K + ks * 32 + acol;
      gld_lds16(gb, lB + ch * 512);
    }
    __syncthreads();
    #pragma unroll
    for (int i = 0; i < 4; ++i) {
      bf16x8 af = *(const bf16x8*)(lA + (wr * 64 + i * 16 + lr) * 32 + lg * 8);
      #pragma unroll
      for (int j = 0; j < 4; ++j) {
        bf16x8 bf = *(const bf16x8*)(lB + (wc * 64 + j * 16 + lr) * 32 + lg * 8);
        acc[i][j] = mfma16(af, bf, acc[i][j]);
      }
    }
  }
  const int row0 = bm + wr * 64, col0 = bn + wc * 64;
  #pragma unroll
  for (int i = 0; i < 4; ++i) {
    #pragma unroll
    for (int j = 0; j < 4; ++j) {
      #pragma unroll
      for (int r = 0; r < 4; ++r) {
        int row = row0 + i * 16 + lg * 4 + r;
        int col = col0 + j * 16 + lr;
        float v = acc[i][j][r];
        if constexpr (EPI == 0) {
          ((u16*)outp)[(size_t)row * N + col] = f2bf(v);
        } else if constexpr (EPI == 1) {
          ((float*)outp)[(size_t)row * N + col] = v;
        } else if constexpr (EPI == 2) {
          v += bias[col];
          float z = 1.5957691216057308f * (v + 0.044715f * v * v * v);
          float t = 1.f - 2.f / (1.f + __expf(z));   // tanh(z/2) safe at +-inf
          ((u16*)outp)[(size_t)row * N + col] = f2bf(0.5f * v * (1.f + t));
        } else {
          v += bias[col];
          int grow = rowOff + row;
          int bt = grow >> 15;
          float gate = mods[bt * 3072 + 2560 + col];
          ((float*)outp)[(size_t)grow * 512 + col] =
              x1[(size_t)grow * 512 + col] + gate * v;
        }
      }
    }
  }
}

// ---------------- rope + pack q/k into [sel][h][p][d] ----------------

__global__ __launch_bounds__(256) void ropepack_k(const u16* __restrict__ qkv,
    const float* __restrict__ cq, const float* __restrict__ sq,
    const float* __restrict__ ck, const float* __restrict__ sk,
    u16* __restrict__ qb, u16* __restrict__ kb) {
  int T = blockIdx.x * 256 + threadIdx.x;  // 32768 * 128
  int row = T >> 7, oct = T & 127;
  int c0 = oct * 8;
  int sel = row >> 6, p = row & 63;
  int isk = (c0 >= 512);
  int chn = c0 & 511;
  int h = chn >> 6, d0 = chn & 63;
  int lower = (d0 < 32);
  const u16* base = qkv + (size_t)row * 1536 + (isk ? 512 : 0) + h * 64;
  u16 vm[8], vp[8];
  *(uint4*)vm = *(const uint4*)(base + d0);
  *(uint4*)vp = *(const uint4*)(base + (d0 ^ 32));
  const float* cT = (isk ? ck : cq) + p * 64 + d0;
  const float* sT = (isk ? sk : sq) + p * 64 + d0;
  float scale = isk ? 1.f : 0.125f;  // fold 1/sqrt(dh) into q
  u16 o[8];
  #pragma unroll
  for (int j = 0; j < 8; ++j) {
    float a = bf2f(vm[j]), b = bf2f(vp[j]);
    float r = a * cT[j] + (lower ? -b : b) * sT[j];
    o[j] = f2bf(r * scale);
  }
  u16* dst = (isk ? kb : qb) + (((size_t)sel * 8 + h) * 64 + p) * 64 + d0;
  *(uint4*)dst = *(uint4*)o;
}

// ---------------- v transpose: qkv v-part -> vT [sel][h][d][p] ----------------

__global__ __launch_bounds__(256) void vtrans_k(const u16* __restrict__ qkv,
                                                u16* __restrict__ vT) {
  __shared__ u16 tb[64 * 65];
  int sel = blockIdx.x >> 3, h = blockIdx.x & 7;
  int tid = threadIdx.x;
  int p = tid >> 2, q16 = (tid & 3) * 16;
  const u16* src = qkv + (size_t)(sel * 64 + p) * 1536 + 1024 + h * 64 + q16;
  u16 ld[16];
  *(uint4*)&ld[0] = *(const uint4*)src;
  *(uint4*)&ld[8] = *(const uint4*)(src + 8);
  #pragma unroll
  for (int j = 0; j < 16; ++j) tb[p * 65 + q16 + j] = ld[j];
  __syncthreads();
  int d = tid >> 2, po = (tid & 3) * 16;
  u16 o[16];
  #pragma unroll
  for (int j = 0; j < 16; ++j) o[j] = tb[(po + j) * 65 + d];
  u16* dst = vT + (((size_t)sel * 8 + h) * 64 + d) * 64 + po;
  *(uint4*)dst = *(uint4*)&o[0];
  *(uint4*)(dst + 8) = *(uint4*)&o[8];
}

// ---------------- attention: one WG per (sel, head) ----------------
// P staged per-neighbor (16x64 per wave), double-buffered, wave-local sync only.

__global__ __launch_bounds__(256) void attn_k(const u16* __restrict__ qbuf,
    const u16* __restrict__ kfull, const u16* __restrict__ vT,
    const u16* __restrict__ kempty, const u16* __restrict__ vTempty,
    const int* __restrict__ nbrs, const int* __restrict__ selmap,
    u16* __restrict__ attnout) {
  __shared__ u16 Pl[4][2][16][72];   // 18432 B
  int sel = blockIdx.x >> 3, h = blockIdx.x & 7;
  int w = threadIdx.x >> 6, l = threadIdx.x & 63;
  int lr = l & 15, lg = l >> 4;

  const u16* qb = qbuf + (((size_t)sel * 8 + h) * 64 + w * 16) * 64;
  bf16x8 qf0 = *(const bf16x8*)(qb + lr * 64 + lg * 8);
  bf16x8 qf1 = *(const bf16x8*)(qb + lr * 64 + 32 + lg * 8);

  const u16* kb[7];
  const u16* vb[7];
  #pragma unroll
  for (int n = 0; n < 7; ++n) {
    int gg = nbrs[sel * 7 + n];
    int m = selmap[gg];
    size_t hoff = (size_t)h * 4096;
    kb[n] = (m >= 0) ? kfull + (size_t)m * 8 * 4096 + hoff : kempty + hoff;
    vb[n] = (m >= 0) ? vT + (size_t)m * 8 * 4096 + hoff : vTempty + hoff;
  }

  f32x4 sa[7][4];
  #pragma unroll
  for (int n = 0; n < 7; ++n)
    #pragma unroll
    for (int ct = 0; ct < 4; ++ct) sa[n][ct] = (f32x4){0.f, 0.f, 0.f, 0.f};

  #pragma unroll
  for (int n = 0; n < 7; ++n) {
    #pragma unroll
    for (int ct = 0; ct < 4; ++ct) {
      bf16x8 b0 = *(const bf16x8*)(kb[n] + (ct * 16 + lr) * 64 + lg * 8);
      bf16x8 b1 = *(const bf16x8*)(kb[n] + (ct * 16 + lr) * 64 + 32 + lg * 8);
      sa[n][ct] = mfma16(qf0, b0, sa[n][ct]);
      sa[n][ct] = mfma16(qf1, b1, sa[n][ct]);
    }
  }

  float mx[4] = {-1e30f, -1e30f, -1e30f, -1e30f};
  #pragma unroll
  for (int n = 0; n < 7; ++n)
    #pragma unroll
    for (int ct = 0; ct < 4; ++ct)
      #pragma unroll
      for (int r = 0; r < 4; ++r) mx[r] = fmaxf(mx[r], sa[n][ct][r]);
  #pragma unroll
  for (int r = 0; r < 4; ++r) {
    #pragma unroll
    for (int m = 1; m < 16; m <<= 1) mx[r] = fmaxf(mx[r], __shfl_xor(mx[r], m, 64));
  }
  float sm[4] = {0.f, 0.f, 0.f, 0.f};
  #pragma unroll
  for (int n = 0; n < 7; ++n)
    #pragma unroll
    for (int ct = 0; ct < 4; ++ct)
      #pragma unroll
      for (int r = 0; r < 4; ++r) {
        float e = __expf(sa[n][ct][r] - mx[r]);
        sa[n][ct][r] = e;
        sm[r] += e;
      }
  #pragma unroll
  for (int r = 0; r < 4; ++r) {
    #pragma unroll
    for (int m = 1; m < 16; m <<= 1) sm[r] += __shfl_xor(sm[r], m, 64);
  }

  // PV, per-neighbor P staging (wave-local; no __syncthreads needed)
  f32x4 o[4];
  #pragma unroll
  for (int ct = 0; ct < 4; ++ct) o[ct] = (f32x4){0.f, 0.f, 0.f, 0.f};
  #pragma unroll
  for (int n = 0; n < 7; ++n) {
    #pragma unroll
    for (int ct = 0; ct < 4; ++ct)
      #pragma unroll
      for (int r = 0; r < 4; ++r)
        Pl[w][n & 1][lg * 4 + r][ct * 16 + lr] = f2bf(sa[n][ct][r]);
    asm volatile("s_waitcnt lgkmcnt(0)" ::: "memory");
    bf16x8 pa0 = *(const bf16x8*)&Pl[w][n & 1][lr][lg * 8];
    bf16x8 pa1 = *(const bf16x8*)&Pl[w][n & 1][lr][32 + lg * 8];
    #pragma unroll
    for (int ct = 0; ct < 4; ++ct) {
      bf16x8 v0 = *(const bf16x8*)(vb[n] + (ct * 16 + lr) * 64 + lg * 8);
      bf16x8 v1 = *(const bf16x8*)(vb[n] + (ct * 16 + lr) * 64 + 32 + lg * 8);
      o[ct] = mfma16(pa0, v0, o[ct]);
      o[ct] = mfma16(pa1, v1, o[ct]);
    }
  }
  float inv[4];
  #pragma unroll
  for (int r = 0; r < 4; ++r) inv[r] = 1.f / sm[r];
  #pragma unroll
  for (int ct = 0; ct < 4; ++ct)
    #pragma unroll
    for (int r = 0; r < 4; ++r) {
      int p = w * 16 + lg * 4 + r;
      int d = ct * 16 + lr;
      attnout[((size_t)sel * 64 + p) * 512 + h * 64 + d] = f2bf(o[ct][r] * inv[r]);
    }
}

// ---------------- x1 = x + gate*proj, then LN2 + modulate -> x2 ----------------

__global__ __launch_bounds__(256) void x1ln2_k(const float* __restrict__ x,
    const float* __restrict__ opout, const int* __restrict__ selmap,
    const float* __restrict__ mods, const float* __restrict__ nw,
    float* __restrict__ x1, u16* __restrict__ x2) {
  int row = blockIdx.x * 4 + (threadIdx.x >> 6);  // 0..65535
  int t = threadIdx.x & 63;
  int bt = row >> 15, s = row & 32767;
  int i1 = s >> 12, p1 = (s >> 10) & 3, i2 = (s >> 7) & 7,
      p2 = (s >> 5) & 3, i3 = (s >> 2) & 7, p3 = s & 3;
  int blk = (((i1 << 3) | i2) << 3) | i3;
  int m = selmap[(bt << 9) | blk];
  int d0 = t * 8;
  const float* src = x + (size_t)row * 512 + d0;
  float4 a = *(const float4*)src;
  float4 b = *(const float4*)(src + 4);
  float v[8] = {a.x, a.y, a.z, a.w, b.x, b.y, b.z, b.w};
  const float* mb = mods + bt * 3072;
  if (m >= 0) {
    int p = (p1 << 4) | (p2 << 2) | p3;
    const float* op = opout + ((size_t)m * 64 + p) * 512 + d0;
    float4 oa = *(const float4*)op;
    float4 ob = *(const float4*)(op + 4);
    float ov[8] = {oa.x, oa.y, oa.z, oa.w, ob.x, ob.y, ob.z, ob.w};
    #pragma unroll
    for (int j = 0; j < 8; ++j) v[j] += mb[1024 + d0 + j] * ov[j];
  }
  float4 s0 = {v[0], v[1], v[2], v[3]}, s1 = {v[4], v[5], v[6], v[7]};
  *(float4*)(x1 + (size_t)row * 512 + d0) = s0;
  *(float4*)(x1 + (size_t)row * 512 + d0 + 4) = s1;
  float sum = 0.f, sq = 0.f;
  #pragma unroll
  for (int j = 0; j < 8; ++j) { sum += v[j]; sq += v[j] * v[j]; }
  #pragma unroll
  for (int mm = 1; mm < 64; mm <<= 1) {
    sum += __shfl_xor(sum, mm, 64);
    sq  += __shfl_xor(sq, mm, 64);
  }
  float mean = sum * (1.f / 512.f);
  float var = sq * (1.f / 512.f) - mean * mean;
  float rstd = rsqrtf(var + 1e-5f);
  u16 o[8];
  #pragma unroll
  for (int j = 0; j < 8; ++j) {
    int d = d0 + j;
    float xn = (v[j] - mean) * rstd * nw[d];
    o[j] = f2bf(xn * (1.f + mb[2048 + d]) + mb[1536 + d]);
  }
  *(uint4*)(x2 + (size_t)row * 512 + d0) = *(uint4*)o;
}

// ---------------- launcher ----------------

extern "C" void kernel_launch(void* const* d_in, const int* in_sizes, int n_in,
                              void* d_out, int out_size, void* d_ws, size_t ws_size,
                              hipStream_t stream) {
  const float* x    = (const float*)d_in[0];
  const float* c    = (const float*)d_in[1];
  const float* cosq = (const float*)d_in[2];
  const float* sinq = (const float*)d_in[3];
  const float* cosk = (const float*)d_in[4];
  const float* sink = (const float*)d_in[5];
  const int* nzb    = (const int*)d_in[6];
  const int* nbrs   = (const int*)d_in[7];
  const float* norm1_w = (const float*)d_in[11];
  const float* qkv_w   = (const float*)d_in[12];
  const float* out_w   = (const float*)d_in[13];
  const float* norm2_w = (const float*)d_in[14];
  const float* mlp_w1  = (const float*)d_in[15];
  const float* mlp_b1  = (const float*)d_in[16];
  const float* mlp_w2  = (const float*)d_in[17];
  const float* mlp_b2  = (const float*)d_in[18];
  const float* adaln_w = (const float*)d_in[19];
  const float* adaln_b = (const float*)d_in[20];
  const float* kv_e    = (const float*)d_in[21];
  float* outp = (float*)d_out;
  char* ws = (char*)d_ws;

  const size_t MB = 1024ull * 1024ull;
  // region map (with safe lifetime-based aliasing), total ~423 MiB:
  u16*   qkvb    = (u16*)(ws + 0);            // 96 MiB  (dead after ropepack/vtrans)
  float* opout   = (float*)(ws + 0);          // 64 MiB  (written at out-proj)
  u16*   xm      = (u16*)(ws + 96 * MB);      // 32 MiB  (dead after qkv gemm)
  u16*   attnout = (u16*)(ws + 96 * MB);      // 32 MiB  (written at attn)
  u16*   qb      = (u16*)(ws + 128 * MB);     // 32 MiB  (dead after attn)
  u16*   hidden  = (u16*)(ws + 128 * MB);     // 64 MiB  (written at mlp1; spans qb+kf)
  u16*   kf      = (u16*)(ws + 160 * MB);     // 32 MiB  (dead after attn)
  u16*   vT      = (u16*)(ws + 192 * MB);     // 32 MiB
  float* x1      = (float*)(ws + 224 * MB);   // 128 MiB
  u16*   x2      = (u16*)(ws + 352 * MB);     // 64 MiB
  char*  S0      = ws + 416 * MB;
  float* mods    = (float*)(S0);              // 24 KiB
  int*   selmap  = (int*)(S0 + 0x8000);       // 4 KiB
  u16*   kempty  = (u16*)(S0 + 0x10000);      // 64 KiB
  u16*   vTempty = (u16*)(S0 + 0x20000);      // 64 KiB
  u16*   qkvw_bf = (u16*)(S0 + 0x30000);              // 1.5 MiB
  u16*   outw_bf = qkvw_bf + (size_t)1536 * 512;      // 0.5 MiB
  u16*   w1_bf   = outw_bf + (size_t)512 * 512;       // 2 MiB
  u16*   w2_bf   = w1_bf + (size_t)2048 * 512;        // 2 MiB

  // prep
  selmap_k<<<1, 1024, 0, stream>>>(nzb, selmap);
  adaln_k<<<dim3(12, 2), 256, 0, stream>>>(c, adaln_w, adaln_b, mods);
  castw_k<<<768, 256, 0, stream>>>(qkv_w, qkvw_bf, 1536 * 512 / 4);
  castw_k<<<256, 256, 0, stream>>>(out_w, outw_bf, 512 * 512 / 4);
  castw_k<<<1024, 256, 0, stream>>>(mlp_w1, w1_bf, 2048 * 512 / 4);
  castw_k<<<1024, 256, 0, stream>>>(mlp_w2, w2_bf, 512 * 2048 / 4);
  kvempty_k<<<128, 256, 0, stream>>>(kv_e, cosk, sink, kempty, vTempty);

  // LN1 + modulate on selected rows
  ln1_k<<<8192, 256, 0, stream>>>(x, norm1_w, mods, nzb, xm);

  // qkv = xm @ qkv_w^T
  gemm_bt<0><<<dim3(256, 12), 256, 0, stream>>>(xm, qkvw_bf, 32768, 1536, 512,
                                                qkvb, nullptr, nullptr, nullptr, 0);
  // rope q/k, pack; transpose v
  ropepack_k<<<16384, 256, 0, stream>>>(qkvb, cosq, sinq, cosk, sink, qb, kf);
  vtrans_k<<<4096, 256, 0, stream>>>(qkvb, vT);

  // attention
  attn_k<<<4096, 256, 0, stream>>>(qb, kf, vT, kempty, vTempty, nbrs, selmap, attnout);

  // out projection (selected rows only)
  gemm_bt<1><<<dim3(256, 4), 256, 0, stream>>>(attnout, outw_bf, 32768, 512, 512,
                                               opout, nullptr, nullptr, nullptr, 0);

  // x1 = x + gate_msa*proj (scattered), LN2 + modulate -> x2
  x1ln2_k<<<16384, 256, 0, stream>>>(x, opout, selmap, mods, norm2_w, x1, x2);

  // MLP, chunked over rows (4 x 16384)
  for (int cchunk = 0; cchunk < 4; ++cchunk) {
    const u16* a1 = x2 + (size_t)cchunk * 16384 * 512;
    gemm_bt<2><<<dim3(128, 16), 256, 0, stream>>>(a1, w1_bf, 16384, 2048, 512,
                                                  hidden, mlp_b1, nullptr, nullptr, 0);
    gemm_bt<3><<<dim3(128, 4), 256, 0, stream>>>(hidden, w2_bf, 16384, 512, 2048,
                                                 outp, mlp_b2, x1, mods,
                                                 cchunk * 16384);
  }
}

// Round 3
// 1063.764 us; speedup vs baseline: 1.0714x; 1.0714x over previous
//
#include <hip/hip_runtime.h>
#include <cstdint>
#include <cstddef>

typedef unsigned short u16;
typedef __attribute__((ext_vector_type(8))) __bf16 bf16x8;
typedef __attribute__((ext_vector_type(4))) float f32x4;

typedef __attribute__((address_space(1))) const void GAS;
typedef __attribute__((address_space(3))) void LAS;

__device__ __forceinline__ void gld_lds16(const void* g, void* l) {
  __builtin_amdgcn_global_load_lds((GAS*)g, (LAS*)l, 16, 0, 0);
}

__device__ __forceinline__ u16 f2bf(float f) {
  union { float f; unsigned u; } x; x.f = f;
  unsigned r = x.u + 0x7FFFu + ((x.u >> 16) & 1u);
  return (u16)(r >> 16);
}
__device__ __forceinline__ float bf2f(u16 s) {
  union { unsigned u; float f; } x; x.u = ((unsigned)s) << 16;
  return x.f;
}
__device__ __forceinline__ f32x4 mfma16(bf16x8 a, bf16x8 b, f32x4 c) {
  return __builtin_amdgcn_mfma_f32_16x16x32_bf16(a, b, c, 0, 0, 0);
}

// ---------------- small prep kernels ----------------

__global__ void selmap_k(const int* __restrict__ nzb, int* __restrict__ map) {
  int t = threadIdx.x;            // 1024 threads
  map[t] = -1;
  __syncthreads();
  if (t < 512) map[nzb[t]] = t;
}

__global__ __launch_bounds__(256) void castw_k(const float* __restrict__ in,
                                               u16* __restrict__ out, int n4) {
  int i = blockIdx.x * 256 + threadIdx.x;
  if (i >= n4) return;
  float4 v = ((const float4*)in)[i];
  u16 o[4] = {f2bf(v.x), f2bf(v.y), f2bf(v.z), f2bf(v.w)};
  ((uint2*)out)[i] = *(uint2*)o;
}

__global__ __launch_bounds__(256) void adaln_k(const float* __restrict__ c,
    const float* __restrict__ w, const float* __restrict__ b, float* __restrict__ mods) {
  int j = blockIdx.x * 256 + threadIdx.x;  // 0..3071
  int bt = blockIdx.y;
  const float4* cr = (const float4*)(c + bt * 512);
  const float4* wr = (const float4*)(w + (size_t)j * 512);
  float s = 0.f;
  #pragma unroll 4
  for (int k = 0; k < 128; ++k) {
    float4 a = wr[k], q = cr[k];
    s += a.x * q.x + a.y * q.y + a.z * q.z + a.w * q.w;
  }
  mods[bt * 3072 + j] = s + b[j];
}

// rope the shared empty-block K, copy/transpose empty V
__global__ __launch_bounds__(256) void kvempty_k(const float* __restrict__ kve,
    const float* __restrict__ cT, const float* __restrict__ sT,
    u16* __restrict__ kempty, u16* __restrict__ vTempty) {
  int T = blockIdx.x * 256 + threadIdx.x;  // 32768
  int h = T >> 12, p = (T >> 6) & 63, d = T & 63;
  float kv = kve[p * 1024 + h * 64 + d];
  float pv = kve[p * 1024 + h * 64 + (d ^ 32)];
  float cs = cT[p * 64 + d], sn = sT[p * 64 + d];
  float r = kv * cs + ((d < 32) ? -pv : pv) * sn;
  kempty[(h * 64 + p) * 64 + d] = f2bf(r);
  vTempty[(h * 64 + d) * 64 + p] = f2bf(kve[p * 1024 + 512 + h * 64 + d]);
}

// ---------------- LN1 + modulate + block-gather (selected rows only) ----------------

__global__ __launch_bounds__(256) void ln1_k(const float* __restrict__ x,
    const float* __restrict__ nw, const float* __restrict__ mods,
    const int* __restrict__ nzb, u16* __restrict__ xm) {
  int row = blockIdx.x * 4 + (threadIdx.x >> 6);  // 0..32767 (sel*64 + p)
  int t = threadIdx.x & 63;
  int sel = row >> 6, p = row & 63;
  int g = nzb[sel];
  int bt = g >> 9, blk = g & 511;
  int s = (blk >> 6) * 4096 + (p >> 4) * 1024 + ((blk >> 3) & 7) * 128
        + ((p >> 2) & 3) * 32 + (blk & 7) * 4 + (p & 3);
  const float* src = x + ((size_t)bt * 32768 + s) * 512;
  int d0 = t * 8;
  float4 a = *(const float4*)(src + d0);
  float4 b = *(const float4*)(src + d0 + 4);
  float v[8] = {a.x, a.y, a.z, a.w, b.x, b.y, b.z, b.w};
  float sum = 0.f, sq = 0.f;
  #pragma unroll
  for (int j = 0; j < 8; ++j) { sum += v[j]; sq += v[j] * v[j]; }
  #pragma unroll
  for (int m = 1; m < 64; m <<= 1) {
    sum += __shfl_xor(sum, m, 64);
    sq  += __shfl_xor(sq, m, 64);
  }
  float mean = sum * (1.f / 512.f);
  float var = sq * (1.f / 512.f) - mean * mean;
  float rstd = rsqrtf(var + 1e-5f);
  const float* mb = mods + bt * 3072;
  u16 o[8];
  #pragma unroll
  for (int j = 0; j < 8; ++j) {
    int d = d0 + j;
    float xn = (v[j] - mean) * rstd * nw[d];
    o[j] = f2bf(xn * (1.f + mb[512 + d]) + mb[d]);
  }
  *(uint4*)(xm + (size_t)row * 512 + d0) = *(uint4*)o;
}

// ---------------- generic bf16 GEMM  C = A @ W^T  (M,N,K % 128,128,32 == 0) ----------------
// EPI: 0 = store bf16; 1 = store f32; 2 = +bias, gelu, store bf16;
//      3 = +bias, out[grow] = x1[grow] + gate_mlp*val (final output)

template <int EPI>
__global__ __launch_bounds__(256) void gemm_bt(const u16* __restrict__ A,
    const u16* __restrict__ W, int M, int N, int K, void* __restrict__ outp,
    const float* __restrict__ bias, const float* __restrict__ x1,
    const float* __restrict__ mods, int rowOff) {
  __shared__ u16 lA[128 * 32];
  __shared__ u16 lB[128 * 32];
  const int bm = blockIdx.x * 128, bn = blockIdx.y * 128;
  const int tid = threadIdx.x;
  const int w = tid >> 6, l = tid & 63;
  const int lr = l & 15, lg = l >> 4;
  const int wr = w >> 1, wc = w & 1;
  f32x4 acc[4][4];
  #pragma unroll
  for (int i = 0; i < 4; ++i)
    #pragma unroll
    for (int j = 0; j < 4; ++j) acc[i][j] = (f32x4){0.f, 0.f, 0.f, 0.f};
  const int nk = K >> 5;
  const int arow = l >> 2;          // 0..15 in chunk
  const int acol = (l & 3) * 8;
  for (int ks = 0; ks < nk; ++ks) {
    __syncthreads();
    #pragma unroll
    for (int cc = 0; cc < 2; ++cc) {
      int ch = w * 2 + cc;
      const u16* ga = A + (size_t)(bm + ch * 16 + arow) * K + ks * 32 + acol;
      gld_lds16(ga, lA + ch * 512);
      const u16* gb = W + (size_t)(bn + ch * 16 + arow) * K + ks * 32 + acol;
      gld_lds16(gb, lB + ch * 512);
    }
    __syncthreads();
    #pragma unroll
    for (int i = 0; i < 4; ++i) {
      bf16x8 af = *(const bf16x8*)(lA + (wr * 64 + i * 16 + lr) * 32 + lg * 8);
      #pragma unroll
      for (int j = 0; j < 4; ++j) {
        bf16x8 bf = *(const bf16x8*)(lB + (wc * 64 + j * 16 + lr) * 32 + lg * 8);
        acc[i][j] = mfma16(af, bf, acc[i][j]);
      }
    }
  }
  const int row0 = bm + wr * 64, col0 = bn + wc * 64;
  #pragma unroll
  for (int i = 0; i < 4; ++i) {
    #pragma unroll
    for (int j = 0; j < 4; ++j) {
      #pragma unroll
      for (int r = 0; r < 4; ++r) {
        int row = row0 + i * 16 + lg * 4 + r;
        int col = col0 + j * 16 + lr;
        float v = acc[i][j][r];
        if constexpr (EPI == 0) {
          ((u16*)outp)[(size_t)row * N + col] = f2bf(v);
        } else if constexpr (EPI == 1) {
          ((float*)outp)[(size_t)row * N + col] = v;
        } else if constexpr (EPI == 2) {
          v += bias[col];
          float z = 1.5957691216057308f * (v + 0.044715f * v * v * v);
          float t = 1.f - 2.f / (1.f + __expf(z));   // tanh(z/2) safe at +-inf
          ((u16*)outp)[(size_t)row * N + col] = f2bf(0.5f * v * (1.f + t));
        } else {
          v += bias[col];
          int grow = rowOff + row;
          int bt = grow >> 15;
          float gate = mods[bt * 3072 + 2560 + col];
          ((float*)outp)[(size_t)grow * 512 + col] =
              x1[(size_t)grow * 512 + col] + gate * v;
        }
      }
    }
  }
}

// ---------------- rope + pack q/k into [sel][h][p][d] ----------------

__global__ __launch_bounds__(256) void ropepack_k(const u16* __restrict__ qkv,
    const float* __restrict__ cq, const float* __restrict__ sq,
    const float* __restrict__ ck, const float* __restrict__ sk,
    u16* __restrict__ qb, u16* __restrict__ kb) {
  int T = blockIdx.x * 256 + threadIdx.x;  // 32768 * 128
  int row = T >> 7, oct = T & 127;
  int c0 = oct * 8;
  int sel = row >> 6, p = row & 63;
  int isk = (c0 >= 512);
  int chn = c0 & 511;
  int h = chn >> 6, d0 = chn & 63;
  int lower = (d0 < 32);
  const u16* base = qkv + (size_t)row * 1536 + (isk ? 512 : 0) + h * 64;
  u16 vm[8], vp[8];
  *(uint4*)vm = *(const uint4*)(base + d0);
  *(uint4*)vp = *(const uint4*)(base + (d0 ^ 32));
  const float* cT = (isk ? ck : cq) + p * 64 + d0;
  const float* sT = (isk ? sk : sq) + p * 64 + d0;
  float scale = isk ? 1.f : 0.125f;  // fold 1/sqrt(dh) into q
  u16 o[8];
  #pragma unroll
  for (int j = 0; j < 8; ++j) {
    float a = bf2f(vm[j]), b = bf2f(vp[j]);
    float r = a * cT[j] + (lower ? -b : b) * sT[j];
    o[j] = f2bf(r * scale);
  }
  u16* dst = (isk ? kb : qb) + (((size_t)sel * 8 + h) * 64 + p) * 64 + d0;
  *(uint4*)dst = *(uint4*)o;
}

// ---------------- v transpose: qkv v-part -> vT [sel][h][d][p] ----------------

__global__ __launch_bounds__(256) void vtrans_k(const u16* __restrict__ qkv,
                                                u16* __restrict__ vT) {
  __shared__ u16 tb[64 * 65];
  int sel = blockIdx.x >> 3, h = blockIdx.x & 7;
  int tid = threadIdx.x;
  int p = tid >> 2, q16 = (tid & 3) * 16;
  const u16* src = qkv + (size_t)(sel * 64 + p) * 1536 + 1024 + h * 64 + q16;
  u16 ld[16];
  *(uint4*)&ld[0] = *(const uint4*)src;
  *(uint4*)&ld[8] = *(const uint4*)(src + 8);
  #pragma unroll
  for (int j = 0; j < 16; ++j) tb[p * 65 + q16 + j] = ld[j];
  __syncthreads();
  int d = tid >> 2, po = (tid & 3) * 16;
  u16 o[16];
  #pragma unroll
  for (int j = 0; j < 16; ++j) o[j] = tb[(po + j) * 65 + d];
  u16* dst = vT + (((size_t)sel * 8 + h) * 64 + d) * 64 + po;
  *(uint4*)dst = *(uint4*)&o[0];
  *(uint4*)(dst + 8) = *(uint4*)&o[8];
}

// ---------------- attention: flash-style over neighbors ----------------
// One WG per (sel, head). K double-buffered in LDS (XOR-swizzled via pre-swizzled
// global src), counted vmcnt(2), raw barriers. V read direct from global.
// Online softmax: per-neighbor s4[4] + running (m, l, O) -> no register spill.

__global__ __launch_bounds__(256, 4) void attn_k(const u16* __restrict__ qbuf,
    const u16* __restrict__ kfull, const u16* __restrict__ vT,
    const u16* __restrict__ kempty, const u16* __restrict__ vTempty,
    const int* __restrict__ nbrs, const int* __restrict__ selmap,
    u16* __restrict__ attnout) {
  __shared__ u16 KB[2][4096];        // 16 KiB, K tile [64 k][64 d], chunk^=(row&7)
  __shared__ u16 Pl[4][16][72];      // 9.2 KiB, per-wave P
  int bid = blockIdx.x;
  int swz = (bid & 7) * 512 + (bid >> 3);   // XCD-chunked (4096 % 8 == 0, bijective)
  int sel = swz >> 3, h = swz & 7;
  int tid = threadIdx.x;
  int w = tid >> 6, l = tid & 63, lr = l & 15, lg = l >> 4;

  int mmv[7];
  #pragma unroll
  for (int n = 0; n < 7; ++n) mmv[n] = selmap[nbrs[sel * 7 + n]];

  const u16* qg = qbuf + (((size_t)sel * 8 + h) * 64 + w * 16) * 64;
  bf16x8 qf0 = *(const bf16x8*)(qg + lr * 64 + lg * 8);
  bf16x8 qf1 = *(const bf16x8*)(qg + lr * 64 + 32 + lg * 8);

  // staging: LDS slot s = i*256+tid holds K[row=s>>3][chunk=(s&7)^(row&7)]
  int srow = tid >> 3;
  int soff = srow * 64 + (((tid & 7) ^ (srow & 7)) << 3);  // u16 units; i=1: +2048
  size_t hoff = (size_t)h * 4096;

  {
    const u16* kp = (mmv[0] >= 0) ? kfull + (size_t)mmv[0] * 32768 + hoff
                                  : kempty + hoff;
    gld_lds16(kp + soff, &KB[0][w * 512]);
    gld_lds16(kp + soff + 2048, &KB[0][2048 + w * 512]);
  }

  f32x4 o[4];
  float mrun[4], lrun[4];
  #pragma unroll
  for (int ct = 0; ct < 4; ++ct) o[ct] = (f32x4){0.f, 0.f, 0.f, 0.f};
  #pragma unroll
  for (int r = 0; r < 4; ++r) { mrun[r] = -1e30f; lrun[r] = 0.f; }

  #pragma unroll
  for (int n = 0; n < 7; ++n) {
    if (n < 6) {
      const u16* kp = (mmv[n + 1] >= 0) ? kfull + (size_t)mmv[n + 1] * 32768 + hoff
                                        : kempty + hoff;
      int b = (n + 1) & 1;
      gld_lds16(kp + soff, &KB[b][w * 512]);
      gld_lds16(kp + soff + 2048, &KB[b][2048 + w * 512]);
      asm volatile("s_waitcnt vmcnt(2)" ::: "memory");
    } else {
      asm volatile("s_waitcnt vmcnt(0)" ::: "memory");
    }
    __builtin_amdgcn_s_barrier();
    __builtin_amdgcn_sched_barrier(0);

    const u16* kl = &KB[n & 1][0];
    const u16* vp = (mmv[n] >= 0) ? vT + (size_t)mmv[n] * 32768 + hoff
                                  : vTempty + hoff;
    // QK^T for this neighbor
    f32x4 s4[4];
    int xr = lr & 7;
    #pragma unroll
    for (int ct = 0; ct < 4; ++ct) {
      int row = ct * 16 + lr;
      bf16x8 b0 = *(const bf16x8*)(kl + row * 64 + ((lg ^ xr) << 3));
      bf16x8 b1 = *(const bf16x8*)(kl + row * 64 + (((lg + 4) ^ xr) << 3));
      f32x4 z = (f32x4){0.f, 0.f, 0.f, 0.f};
      z = mfma16(qf0, b0, z);
      z = mfma16(qf1, b1, z);
      s4[ct] = z;
    }
    // online softmax update
    float rmax[4], sc[4], rs[4];
    #pragma unroll
    for (int r = 0; r < 4; ++r)
      rmax[r] = fmaxf(fmaxf(s4[0][r], s4[1][r]), fmaxf(s4[2][r], s4[3][r]));
    #pragma unroll
    for (int r = 0; r < 4; ++r) {
      #pragma unroll
      for (int ms = 1; ms < 16; ms <<= 1)
        rmax[r] = fmaxf(rmax[r], __shfl_xor(rmax[r], ms, 64));
      float mn = fmaxf(mrun[r], rmax[r]);
      sc[r] = __expf(mrun[r] - mn);
      mrun[r] = mn;
      rs[r] = 0.f;
    }
    #pragma unroll
    for (int ct = 0; ct < 4; ++ct)
      #pragma unroll
      for (int r = 0; r < 4; ++r) {
        float e = __expf(s4[ct][r] - mrun[r]);
        s4[ct][r] = e;
        rs[r] += e;
      }
    #pragma unroll
    for (int r = 0; r < 4; ++r) {
      #pragma unroll
      for (int ms = 1; ms < 16; ms <<= 1) rs[r] += __shfl_xor(rs[r], ms, 64);
      lrun[r] = lrun[r] * sc[r] + rs[r];
    }
    #pragma unroll
    for (int ct = 0; ct < 4; ++ct)
      #pragma unroll
      for (int r = 0; r < 4; ++r) o[ct][r] *= sc[r];
    // P -> LDS (wave-local), then PV with direct-global V
    #pragma unroll
    for (int ct = 0; ct < 4; ++ct)
      #pragma unroll
      for (int r = 0; r < 4; ++r)
        Pl[w][lg * 4 + r][ct * 16 + lr] = f2bf(s4[ct][r]);
    asm volatile("s_waitcnt lgkmcnt(0)" ::: "memory");
    __builtin_amdgcn_sched_barrier(0);
    bf16x8 pa0 = *(const bf16x8*)&Pl[w][lr][lg * 8];
    bf16x8 pa1 = *(const bf16x8*)&Pl[w][lr][32 + lg * 8];
    #pragma unroll
    for (int ct = 0; ct < 4; ++ct) {
      bf16x8 v0 = *(const bf16x8*)(vp + (ct * 16 + lr) * 64 + lg * 8);
      bf16x8 v1 = *(const bf16x8*)(vp + (ct * 16 + lr) * 64 + 32 + lg * 8);
      o[ct] = mfma16(pa0, v0, o[ct]);
      o[ct] = mfma16(pa1, v1, o[ct]);
    }
    asm volatile("" ::: "memory");
    __builtin_amdgcn_s_barrier();     // KB[n&1] free for restage at iter n+1
    __builtin_amdgcn_sched_barrier(0);
  }

  float inv[4];
  #pragma unroll
  for (int r = 0; r < 4; ++r) inv[r] = 1.f / lrun[r];
  #pragma unroll
  for (int ct = 0; ct < 4; ++ct)
    #pragma unroll
    for (int r = 0; r < 4; ++r) {
      int p = w * 16 + lg * 4 + r;
      int d = ct * 16 + lr;
      attnout[((size_t)sel * 64 + p) * 512 + h * 64 + d] = f2bf(o[ct][r] * inv[r]);
    }
}

// ---------------- x1 = x + gate*proj, then LN2 + modulate -> x2 ----------------

__global__ __launch_bounds__(256) void x1ln2_k(const float* __restrict__ x,
    const float* __restrict__ opout, const int* __restrict__ selmap,
    const float* __restrict__ mods, const float* __restrict__ nw,
    float* __restrict__ x1, u16* __restrict__ x2) {
  int row = blockIdx.x * 4 + (threadIdx.x >> 6);  // 0..65535
  int t = threadIdx.x & 63;
  int bt = row >> 15, s = row & 32767;
  int i1 = s >> 12, p1 = (s >> 10) & 3, i2 = (s >> 7) & 7,
      p2 = (s >> 5) & 3, i3 = (s >> 2) & 7, p3 = s & 3;
  int blk = (((i1 << 3) | i2) << 3) | i3;
  int m = selmap[(bt << 9) | blk];
  int d0 = t * 8;
  const float* src = x + (size_t)row * 512 + d0;
  float4 a = *(const float4*)src;
  float4 b = *(const float4*)(src + 4);
  float v[8] = {a.x, a.y, a.z, a.w, b.x, b.y, b.z, b.w};
  const float* mb = mods + bt * 3072;
  if (m >= 0) {
    int p = (p1 << 4) | (p2 << 2) | p3;
    const float* op = opout + ((size_t)m * 64 + p) * 512 + d0;
    float4 oa = *(const float4*)op;
    float4 ob = *(const float4*)(op + 4);
    float ov[8] = {oa.x, oa.y, oa.z, oa.w, ob.x, ob.y, ob.z, ob.w};
    #pragma unroll
    for (int j = 0; j < 8; ++j) v[j] += mb[1024 + d0 + j] * ov[j];
  }
  float4 s0 = {v[0], v[1], v[2], v[3]}, s1 = {v[4], v[5], v[6], v[7]};
  *(float4*)(x1 + (size_t)row * 512 + d0) = s0;
  *(float4*)(x1 + (size_t)row * 512 + d0 + 4) = s1;
  float sum = 0.f, sq = 0.f;
  #pragma unroll
  for (int j = 0; j < 8; ++j) { sum += v[j]; sq += v[j] * v[j]; }
  #pragma unroll
  for (int mm = 1; mm < 64; mm <<= 1) {
    sum += __shfl_xor(sum, mm, 64);
    sq  += __shfl_xor(sq, mm, 64);
  }
  float mean = sum * (1.f / 512.f);
  float var = sq * (1.f / 512.f) - mean * mean;
  float rstd = rsqrtf(var + 1e-5f);
  u16 o[8];
  #pragma unroll
  for (int j = 0; j < 8; ++j) {
    int d = d0 + j;
    float xn = (v[j] - mean) * rstd * nw[d];
    o[j] = f2bf(xn * (1.f + mb[2048 + d]) + mb[1536 + d]);
  }
  *(uint4*)(x2 + (size_t)row * 512 + d0) = *(uint4*)o;
}

// ---------------- launcher ----------------

extern "C" void kernel_launch(void* const* d_in, const int* in_sizes, int n_in,
                              void* d_out, int out_size, void* d_ws, size_t ws_size,
                              hipStream_t stream) {
  const float* x    = (const float*)d_in[0];
  const float* c    = (const float*)d_in[1];
  const float* cosq = (const float*)d_in[2];
  const float* sinq = (const float*)d_in[3];
  const float* cosk = (const float*)d_in[4];
  const float* sink = (const float*)d_in[5];
  const int* nzb    = (const int*)d_in[6];
  const int* nbrs   = (const int*)d_in[7];
  const float* norm1_w = (const float*)d_in[11];
  const float* qkv_w   = (const float*)d_in[12];
  const float* out_w   = (const float*)d_in[13];
  const float* norm2_w = (const float*)d_in[14];
  const float* mlp_w1  = (const float*)d_in[15];
  const float* mlp_b1  = (const float*)d_in[16];
  const float* mlp_w2  = (const float*)d_in[17];
  const float* mlp_b2  = (const float*)d_in[18];
  const float* adaln_w = (const float*)d_in[19];
  const float* adaln_b = (const float*)d_in[20];
  const float* kv_e    = (const float*)d_in[21];
  float* outp = (float*)d_out;
  char* ws = (char*)d_ws;

  const size_t MB = 1024ull * 1024ull;
  // region map (with safe lifetime-based aliasing), total ~423 MiB:
  u16*   qkvb    = (u16*)(ws + 0);            // 96 MiB  (dead after ropepack/vtrans)
  float* opout   = (float*)(ws + 0);          // 64 MiB  (written at out-proj)
  u16*   xm      = (u16*)(ws + 96 * MB);      // 32 MiB  (dead after qkv gemm)
  u16*   attnout = (u16*)(ws + 96 * MB);      // 32 MiB  (written at attn)
  u16*   qb      = (u16*)(ws + 128 * MB);     // 32 MiB  (dead after attn)
  u16*   hidden  = (u16*)(ws + 128 * MB);     // 64 MiB  (written at mlp1; spans qb+kf)
  u16*   kf      = (u16*)(ws + 160 * MB);     // 32 MiB  (dead after attn)
  u16*   vT      = (u16*)(ws + 192 * MB);     // 32 MiB
  float* x1      = (float*)(ws + 224 * MB);   // 128 MiB
  u16*   x2      = (u16*)(ws + 352 * MB);     // 64 MiB
  char*  S0      = ws + 416 * MB;
  float* mods    = (float*)(S0);              // 24 KiB
  int*   selmap  = (int*)(S0 + 0x8000);       // 4 KiB
  u16*   kempty  = (u16*)(S0 + 0x10000);      // 64 KiB
  u16*   vTempty = (u16*)(S0 + 0x20000);      // 64 KiB
  u16*   qkvw_bf = (u16*)(S0 + 0x30000);              // 1.5 MiB
  u16*   outw_bf = qkvw_bf + (size_t)1536 * 512;      // 0.5 MiB
  u16*   w1_bf   = outw_bf + (size_t)512 * 512;       // 2 MiB
  u16*   w2_bf   = w1_bf + (size_t)2048 * 512;        // 2 MiB

  // prep
  selmap_k<<<1, 1024, 0, stream>>>(nzb, selmap);
  adaln_k<<<dim3(12, 2), 256, 0, stream>>>(c, adaln_w, adaln_b, mods);
  castw_k<<<768, 256, 0, stream>>>(qkv_w, qkvw_bf, 1536 * 512 / 4);
  castw_k<<<256, 256, 0, stream>>>(out_w, outw_bf, 512 * 512 / 4);
  castw_k<<<1024, 256, 0, stream>>>(mlp_w1, w1_bf, 2048 * 512 / 4);
  castw_k<<<1024, 256, 0, stream>>>(mlp_w2, w2_bf, 512 * 2048 / 4);
  kvempty_k<<<128, 256, 0, stream>>>(kv_e, cosk, sink, kempty, vTempty);

  // LN1 + modulate on selected rows
  ln1_k<<<8192, 256, 0, stream>>>(x, norm1_w, mods, nzb, xm);

  // qkv = xm @ qkv_w^T
  gemm_bt<0><<<dim3(256, 12), 256, 0, stream>>>(xm, qkvw_bf, 32768, 1536, 512,
                                                qkvb, nullptr, nullptr, nullptr, 0);
  // rope q/k, pack; transpose v
  ropepack_k<<<16384, 256, 0, stream>>>(qkvb, cosq, sinq, cosk, sink, qb, kf);
  vtrans_k<<<4096, 256, 0, stream>>>(qkvb, vT);

  // attention
  attn_k<<<4096, 256, 0, stream>>>(qb, kf, vT, kempty, vTempty, nbrs, selmap, attnout);

  // out projection (selected rows only)
  gemm_bt<1><<<dim3(256, 4), 256, 0, stream>>>(attnout, outw_bf, 32768, 512, 512,
                                               opout, nullptr, nullptr, nullptr, 0);

  // x1 = x + gate_msa*proj (scattered), LN2 + modulate -> x2
  x1ln2_k<<<16384, 256, 0, stream>>>(x, opout, selmap, mods, norm2_w, x1, x2);

  // MLP, chunked over rows (4 x 16384)
  for (int cchunk = 0; cchunk < 4; ++cchunk) {
    const u16* a1 = x2 + (size_t)cchunk * 16384 * 512;
    gemm_bt<2><<<dim3(128, 16), 256, 0, stream>>>(a1, w1_bf, 16384, 2048, 512,
                                                  hidden, mlp_b1, nullptr, nullptr, 0);
    gemm_bt<3><<<dim3(128, 4), 256, 0, stream>>>(hidden, w2_bf, 16384, 512, 2048,
                                                 outp, mlp_b2, x1, mods,
                                                 cchunk * 16384);
  }
}

// Round 4
// 946.574 us; speedup vs baseline: 1.2041x; 1.1238x over previous
//
#include <hip/hip_runtime.h>
#include <cstdint>
#include <cstddef>

typedef unsigned short u16;
typedef __attribute__((ext_vector_type(8))) __bf16 bf16x8;
typedef __attribute__((ext_vector_type(4))) float f32x4;

typedef __attribute__((address_space(1))) const void GAS;
typedef __attribute__((address_space(3))) void LAS;

__device__ __forceinline__ void gld_lds16(const void* g, void* l) {
  __builtin_amdgcn_global_load_lds((GAS*)g, (LAS*)l, 16, 0, 0);
}

__device__ __forceinline__ u16 f2bf(float f) {
  union { float f; unsigned u; } x; x.f = f;
  unsigned r = x.u + 0x7FFFu + ((x.u >> 16) & 1u);
  return (u16)(r >> 16);
}
__device__ __forceinline__ float bf2f(u16 s) {
  union { unsigned u; float f; } x; x.u = ((unsigned)s) << 16;
  return x.f;
}
__device__ __forceinline__ f32x4 mfma16(bf16x8 a, bf16x8 b, f32x4 c) {
  return __builtin_amdgcn_mfma_f32_16x16x32_bf16(a, b, c, 0, 0, 0);
}

// ---------------- small prep kernels ----------------

__global__ void selmap_k(const int* __restrict__ nzb, int* __restrict__ map) {
  int t = threadIdx.x;            // 1024 threads
  map[t] = -1;
  __syncthreads();
  if (t < 512) map[nzb[t]] = t;
}

__global__ __launch_bounds__(256) void castw_k(const float* __restrict__ in,
                                               u16* __restrict__ out, int n4) {
  int i = blockIdx.x * 256 + threadIdx.x;
  if (i >= n4) return;
  float4 v = ((const float4*)in)[i];
  u16 o[4] = {f2bf(v.x), f2bf(v.y), f2bf(v.z), f2bf(v.w)};
  ((uint2*)out)[i] = *(uint2*)o;
}

__global__ __launch_bounds__(256) void adaln_k(const float* __restrict__ c,
    const float* __restrict__ w, const float* __restrict__ b, float* __restrict__ mods) {
  int j = blockIdx.x * 256 + threadIdx.x;  // 0..3071
  int bt = blockIdx.y;
  const float4* cr = (const float4*)(c + bt * 512);
  const float4* wr = (const float4*)(w + (size_t)j * 512);
  float s = 0.f;
  #pragma unroll 4
  for (int k = 0; k < 128; ++k) {
    float4 a = wr[k], q = cr[k];
    s += a.x * q.x + a.y * q.y + a.z * q.z + a.w * q.w;
  }
  mods[bt * 3072 + j] = s + b[j];
}

// rope the shared empty-block K, copy/transpose empty V
__global__ __launch_bounds__(256) void kvempty_k(const float* __restrict__ kve,
    const float* __restrict__ cT, const float* __restrict__ sT,
    u16* __restrict__ kempty, u16* __restrict__ vTempty) {
  int T = blockIdx.x * 256 + threadIdx.x;  // 32768
  int h = T >> 12, p = (T >> 6) & 63, d = T & 63;
  float kv = kve[p * 1024 + h * 64 + d];
  float pv = kve[p * 1024 + h * 64 + (d ^ 32)];
  float cs = cT[p * 64 + d], sn = sT[p * 64 + d];
  float r = kv * cs + ((d < 32) ? -pv : pv) * sn;
  kempty[(h * 64 + p) * 64 + d] = f2bf(r);
  vTempty[(h * 64 + d) * 64 + p] = f2bf(kve[p * 1024 + 512 + h * 64 + d]);
}

// ---------------- LN1 + modulate + block-gather (selected rows only) ----------------

__global__ __launch_bounds__(256) void ln1_k(const float* __restrict__ x,
    const float* __restrict__ nw, const float* __restrict__ mods,
    const int* __restrict__ nzb, u16* __restrict__ xm) {
  int row = blockIdx.x * 4 + (threadIdx.x >> 6);  // 0..32767 (sel*64 + p)
  int t = threadIdx.x & 63;
  int sel = row >> 6, p = row & 63;
  int g = nzb[sel];
  int bt = g >> 9, blk = g & 511;
  int s = (blk >> 6) * 4096 + (p >> 4) * 1024 + ((blk >> 3) & 7) * 128
        + ((p >> 2) & 3) * 32 + (blk & 7) * 4 + (p & 3);
  const float* src = x + ((size_t)bt * 32768 + s) * 512;
  int d0 = t * 8;
  float4 a = *(const float4*)(src + d0);
  float4 b = *(const float4*)(src + d0 + 4);
  float v[8] = {a.x, a.y, a.z, a.w, b.x, b.y, b.z, b.w};
  float sum = 0.f, sq = 0.f;
  #pragma unroll
  for (int j = 0; j < 8; ++j) { sum += v[j]; sq += v[j] * v[j]; }
  #pragma unroll
  for (int m = 1; m < 64; m <<= 1) {
    sum += __shfl_xor(sum, m, 64);
    sq  += __shfl_xor(sq, m, 64);
  }
  float mean = sum * (1.f / 512.f);
  float var = sq * (1.f / 512.f) - mean * mean;
  float rstd = rsqrtf(var + 1e-5f);
  const float* mb = mods + bt * 3072;
  u16 o[8];
  #pragma unroll
  for (int j = 0; j < 8; ++j) {
    int d = d0 + j;
    float xn = (v[j] - mean) * rstd * nw[d];
    o[j] = f2bf(xn * (1.f + mb[512 + d]) + mb[d]);
  }
  *(uint4*)(xm + (size_t)row * 512 + d0) = *(uint4*)o;
}

// ---------------- 256x256 bf16 GEMM  C = A @ W^T, BK=64, 8 waves ----------------
// Double-buffered LDS (128 KiB), counted vmcnt(8), raw barriers, XOR-swizzled
// LDS layout (chunk c of row r stored at c^(r&7); pre-swizzled global source).
// EPI: 0 = store bf16; 1 = store f32; 2 = +bias, gelu, store bf16;
//      3 = +bias, out = bf2f(x1) + gate_mlp*val (final output)

template <int EPI>
__global__ __launch_bounds__(512, 2) void gemm256(const u16* __restrict__ A,
    const u16* __restrict__ W, int M, int N, int K, void* __restrict__ outp,
    const float* __restrict__ bias, const u16* __restrict__ x1,
    const float* __restrict__ mods, int rowOff, int NB) {
  __shared__ u16 L[65536];               // 128 KiB: [buf][A|B][16384]
  const int nwg = gridDim.x;
  const int cpx = nwg >> 3;
  const int tile = ((int)blockIdx.x & 7) * cpx + ((int)blockIdx.x >> 3);
  const int bm = (tile / NB) * 256, bn = (tile % NB) * 256;
  const int tid = threadIdx.x;
  const int w = tid >> 6, l = tid & 63, lr = l & 15, lg = l >> 4;
  const int wr = w >> 2, wc = w & 3;

  // staging slots: slot s=(i*512+tid) -> LDS (row=s>>3, cpos=s&7); global chunk = cpos^(row&7)
  const u16* ga[4];
  const u16* gb[4];
  #pragma unroll
  for (int i = 0; i < 4; ++i) {
    int s = i * 512 + tid;
    int r = s >> 3, c = (s & 7) ^ (r & 7);
    ga[i] = A + (size_t)(bm + r) * K + c * 8;
    gb[i] = W + (size_t)(bn + r) * K + c * 8;
  }

  f32x4 acc[8][4];
  #pragma unroll
  for (int i = 0; i < 8; ++i)
    #pragma unroll
    for (int j = 0; j < 4; ++j) acc[i][j] = (f32x4){0.f, 0.f, 0.f, 0.f};

  auto STAGE = [&](int kt, int buf) {
    u16* lb = L + buf * 32768;
    #pragma unroll
    for (int i = 0; i < 4; ++i) {
      gld_lds16(ga[i] + (size_t)kt * 64, lb + (i * 512 + tid) * 8);
      gld_lds16(gb[i] + (size_t)kt * 64, lb + 16384 + (i * 512 + tid) * 8);
    }
  };

  auto COMPUTE = [&](int buf) {
    const u16* LA = L + buf * 32768;
    const u16* LB = LA + 16384;
    bf16x8 bf[4][2];
    #pragma unroll
    for (int nf = 0; nf < 4; ++nf) {
      int Rb = wc * 64 + nf * 16 + lr;
      const u16* pb = LB + Rb * 64;
      int sw = Rb & 7;
      bf[nf][0] = *(const bf16x8*)(pb + ((lg ^ sw) << 3));
      bf[nf][1] = *(const bf16x8*)(pb + (((lg + 4) ^ sw) << 3));
    }
    __builtin_amdgcn_s_setprio(1);
    #pragma unroll
    for (int mf = 0; mf < 8; ++mf) {
      int Ra = wr * 128 + mf * 16 + lr;
      const u16* pa = LA + Ra * 64;
      int sw = Ra & 7;
      bf16x8 a0 = *(const bf16x8*)(pa + ((lg ^ sw) << 3));
      bf16x8 a1 = *(const bf16x8*)(pa + (((lg + 4) ^ sw) << 3));
      #pragma unroll
      for (int nf = 0; nf < 4; ++nf) {
        acc[mf][nf] = mfma16(a0, bf[nf][0], acc[mf][nf]);
        acc[mf][nf] = mfma16(a1, bf[nf][1], acc[mf][nf]);
      }
    }
    __builtin_amdgcn_s_setprio(0);
  };

  const int NT = K >> 6;
  STAGE(0, 0);
  for (int t = 0; t < NT - 1; ++t) {
    STAGE(t + 1, (t + 1) & 1);
    asm volatile("s_waitcnt vmcnt(8)" ::: "memory");
    __builtin_amdgcn_s_barrier();
    asm volatile("" ::: "memory");
    COMPUTE(t & 1);
    asm volatile("" ::: "memory");
    __builtin_amdgcn_s_barrier();
  }
  asm volatile("s_waitcnt vmcnt(0)" ::: "memory");
  __builtin_amdgcn_s_barrier();
  asm volatile("" ::: "memory");
  COMPUTE((NT - 1) & 1);

  const int row0 = bm + wr * 128, col0 = bn + wc * 64;
  #pragma unroll
  for (int mf = 0; mf < 8; ++mf) {
    #pragma unroll
    for (int nf = 0; nf < 4; ++nf) {
      #pragma unroll
      for (int j = 0; j < 4; ++j) {
        int row = row0 + mf * 16 + lg * 4 + j;
        int col = col0 + nf * 16 + lr;
        float v = acc[mf][nf][j];
        if constexpr (EPI == 0) {
          ((u16*)outp)[(size_t)row * N + col] = f2bf(v);
        } else if constexpr (EPI == 1) {
          ((float*)outp)[(size_t)row * N + col] = v;
        } else if constexpr (EPI == 2) {
          v += bias[col];
          float z = 1.5957691216057308f * (v + 0.044715f * v * v * v);
          float t = 1.f - 2.f / (1.f + __expf(z));   // tanh(z/2) safe at +-inf
          ((u16*)outp)[(size_t)row * N + col] = f2bf(0.5f * v * (1.f + t));
        } else {
          v += bias[col];
          int grow = rowOff + row;
          int bt = grow >> 15;
          float gate = mods[bt * 3072 + 2560 + col];
          ((float*)outp)[(size_t)grow * 512 + col] =
              bf2f(x1[(size_t)grow * 512 + col]) + gate * v;
        }
      }
    }
  }
}

// ---------------- rope + pack q/k into [sel][h][p][d] ----------------

__global__ __launch_bounds__(256) void ropepack_k(const u16* __restrict__ qkv,
    const float* __restrict__ cq, const float* __restrict__ sq,
    const float* __restrict__ ck, const float* __restrict__ sk,
    u16* __restrict__ qb, u16* __restrict__ kb) {
  int T = blockIdx.x * 256 + threadIdx.x;  // 32768 * 128
  int row = T >> 7, oct = T & 127;
  int c0 = oct * 8;
  int sel = row >> 6, p = row & 63;
  int isk = (c0 >= 512);
  int chn = c0 & 511;
  int h = chn >> 6, d0 = chn & 63;
  int lower = (d0 < 32);
  const u16* base = qkv + (size_t)row * 1536 + (isk ? 512 : 0) + h * 64;
  u16 vm[8], vp[8];
  *(uint4*)vm = *(const uint4*)(base + d0);
  *(uint4*)vp = *(const uint4*)(base + (d0 ^ 32));
  const float* cT = (isk ? ck : cq) + p * 64 + d0;
  const float* sT = (isk ? sk : sq) + p * 64 + d0;
  float scale = isk ? 1.f : 0.125f;  // fold 1/sqrt(dh) into q
  u16 o[8];
  #pragma unroll
  for (int j = 0; j < 8; ++j) {
    float a = bf2f(vm[j]), b = bf2f(vp[j]);
    float r = a * cT[j] + (lower ? -b : b) * sT[j];
    o[j] = f2bf(r * scale);
  }
  u16* dst = (isk ? kb : qb) + (((size_t)sel * 8 + h) * 64 + p) * 64 + d0;
  *(uint4*)dst = *(uint4*)o;
}

// ---------------- v transpose: qkv v-part -> vT [sel][h][d][p] ----------------

__global__ __launch_bounds__(256) void vtrans_k(const u16* __restrict__ qkv,
                                                u16* __restrict__ vT) {
  __shared__ u16 tb[64 * 65];
  int sel = blockIdx.x >> 3, h = blockIdx.x & 7;
  int tid = threadIdx.x;
  int p = tid >> 2, q16 = (tid & 3) * 16;
  const u16* src = qkv + (size_t)(sel * 64 + p) * 1536 + 1024 + h * 64 + q16;
  u16 ld[16];
  *(uint4*)&ld[0] = *(const uint4*)src;
  *(uint4*)&ld[8] = *(const uint4*)(src + 8);
  #pragma unroll
  for (int j = 0; j < 16; ++j) tb[p * 65 + q16 + j] = ld[j];
  __syncthreads();
  int d = tid >> 2, po = (tid & 3) * 16;
  u16 o[16];
  #pragma unroll
  for (int j = 0; j < 16; ++j) o[j] = tb[(po + j) * 65 + d];
  u16* dst = vT + (((size_t)sel * 8 + h) * 64 + d) * 64 + po;
  *(uint4*)dst = *(uint4*)&o[0];
  *(uint4*)(dst + 8) = *(uint4*)&o[8];
}

// ---------------- attention: flash-style over neighbors ----------------

__global__ __launch_bounds__(256, 4) void attn_k(const u16* __restrict__ qbuf,
    const u16* __restrict__ kfull, const u16* __restrict__ vT,
    const u16* __restrict__ kempty, const u16* __restrict__ vTempty,
    const int* __restrict__ nbrs, const int* __restrict__ selmap,
    u16* __restrict__ attnout) {
  __shared__ u16 KB[2][4096];        // 16 KiB, K tile [64 k][64 d], chunk^=(row&7)
  __shared__ u16 Pl[4][16][72];      // 9.2 KiB, per-wave P
  int bid = blockIdx.x;
  int swz = (bid & 7) * 512 + (bid >> 3);   // XCD-chunked (4096 % 8 == 0, bijective)
  int sel = swz >> 3, h = swz & 7;
  int tid = threadIdx.x;
  int w = tid >> 6, l = tid & 63, lr = l & 15, lg = l >> 4;

  int mmv[7];
  #pragma unroll
  for (int n = 0; n < 7; ++n) mmv[n] = selmap[nbrs[sel * 7 + n]];

  const u16* qg = qbuf + (((size_t)sel * 8 + h) * 64 + w * 16) * 64;
  bf16x8 qf0 = *(const bf16x8*)(qg + lr * 64 + lg * 8);
  bf16x8 qf1 = *(const bf16x8*)(qg + lr * 64 + 32 + lg * 8);

  // staging: LDS slot s = i*256+tid holds K[row=s>>3][chunk=(s&7)^(row&7)]
  int srow = tid >> 3;
  int soff = srow * 64 + (((tid & 7) ^ (srow & 7)) << 3);  // u16 units; i=1: +2048
  size_t hoff = (size_t)h * 4096;

  {
    const u16* kp = (mmv[0] >= 0) ? kfull + (size_t)mmv[0] * 32768 + hoff
                                  : kempty + hoff;
    gld_lds16(kp + soff, &KB[0][w * 512]);
    gld_lds16(kp + soff + 2048, &KB[0][2048 + w * 512]);
  }

  f32x4 o[4];
  float mrun[4], lrun[4];
  #pragma unroll
  for (int ct = 0; ct < 4; ++ct) o[ct] = (f32x4){0.f, 0.f, 0.f, 0.f};
  #pragma unroll
  for (int r = 0; r < 4; ++r) { mrun[r] = -1e30f; lrun[r] = 0.f; }

  #pragma unroll
  for (int n = 0; n < 7; ++n) {
    if (n < 6) {
      const u16* kp = (mmv[n + 1] >= 0) ? kfull + (size_t)mmv[n + 1] * 32768 + hoff
                                        : kempty + hoff;
      int b = (n + 1) & 1;
      gld_lds16(kp + soff, &KB[b][w * 512]);
      gld_lds16(kp + soff + 2048, &KB[b][2048 + w * 512]);
      asm volatile("s_waitcnt vmcnt(2)" ::: "memory");
    } else {
      asm volatile("s_waitcnt vmcnt(0)" ::: "memory");
    }
    __builtin_amdgcn_s_barrier();
    __builtin_amdgcn_sched_barrier(0);

    const u16* kl = &KB[n & 1][0];
    const u16* vp = (mmv[n] >= 0) ? vT + (size_t)mmv[n] * 32768 + hoff
                                  : vTempty + hoff;
    // QK^T for this neighbor
    f32x4 s4[4];
    int xr = lr & 7;
    #pragma unroll
    for (int ct = 0; ct < 4; ++ct) {
      int row = ct * 16 + lr;
      bf16x8 b0 = *(const bf16x8*)(kl + row * 64 + ((lg ^ xr) << 3));
      bf16x8 b1 = *(const bf16x8*)(kl + row * 64 + (((lg + 4) ^ xr) << 3));
      f32x4 z = (f32x4){0.f, 0.f, 0.f, 0.f};
      z = mfma16(qf0, b0, z);
      z = mfma16(qf1, b1, z);
      s4[ct] = z;
    }
    // online softmax update
    float rmax[4], sc[4], rs[4];
    #pragma unroll
    for (int r = 0; r < 4; ++r)
      rmax[r] = fmaxf(fmaxf(s4[0][r], s4[1][r]), fmaxf(s4[2][r], s4[3][r]));
    #pragma unroll
    for (int r = 0; r < 4; ++r) {
      #pragma unroll
      for (int ms = 1; ms < 16; ms <<= 1)
        rmax[r] = fmaxf(rmax[r], __shfl_xor(rmax[r], ms, 64));
      float mn = fmaxf(mrun[r], rmax[r]);
      sc[r] = __expf(mrun[r] - mn);
      mrun[r] = mn;
      rs[r] = 0.f;
    }
    #pragma unroll
    for (int ct = 0; ct < 4; ++ct)
      #pragma unroll
      for (int r = 0; r < 4; ++r) {
        float e = __expf(s4[ct][r] - mrun[r]);
        s4[ct][r] = e;
        rs[r] += e;
      }
    #pragma unroll
    for (int r = 0; r < 4; ++r) {
      #pragma unroll
      for (int ms = 1; ms < 16; ms <<= 1) rs[r] += __shfl_xor(rs[r], ms, 64);
      lrun[r] = lrun[r] * sc[r] + rs[r];
    }
    #pragma unroll
    for (int ct = 0; ct < 4; ++ct)
      #pragma unroll
      for (int r = 0; r < 4; ++r) o[ct][r] *= sc[r];
    // P -> LDS (wave-local), then PV with direct-global V
    #pragma unroll
    for (int ct = 0; ct < 4; ++ct)
      #pragma unroll
      for (int r = 0; r < 4; ++r)
        Pl[w][lg * 4 + r][ct * 16 + lr] = f2bf(s4[ct][r]);
    asm volatile("s_waitcnt lgkmcnt(0)" ::: "memory");
    __builtin_amdgcn_sched_barrier(0);
    bf16x8 pa0 = *(const bf16x8*)&Pl[w][lr][lg * 8];
    bf16x8 pa1 = *(const bf16x8*)&Pl[w][lr][32 + lg * 8];
    #pragma unroll
    for (int ct = 0; ct < 4; ++ct) {
      bf16x8 v0 = *(const bf16x8*)(vp + (ct * 16 + lr) * 64 + lg * 8);
      bf16x8 v1 = *(const bf16x8*)(vp + (ct * 16 + lr) * 64 + 32 + lg * 8);
      o[ct] = mfma16(pa0, v0, o[ct]);
      o[ct] = mfma16(pa1, v1, o[ct]);
    }
    asm volatile("" ::: "memory");
    __builtin_amdgcn_s_barrier();     // KB[n&1] free for restage at iter n+1
    __builtin_amdgcn_sched_barrier(0);
  }

  float inv[4];
  #pragma unroll
  for (int r = 0; r < 4; ++r) inv[r] = 1.f / lrun[r];
  #pragma unroll
  for (int ct = 0; ct < 4; ++ct)
    #pragma unroll
    for (int r = 0; r < 4; ++r) {
      int p = w * 16 + lg * 4 + r;
      int d = ct * 16 + lr;
      attnout[((size_t)sel * 64 + p) * 512 + h * 64 + d] = f2bf(o[ct][r] * inv[r]);
    }
}

// ---------------- x1 = x + gate*proj (bf16), then LN2 + modulate -> x2 ----------------

__global__ __launch_bounds__(256) void x1ln2_k(const float* __restrict__ x,
    const float* __restrict__ opout, const int* __restrict__ selmap,
    const float* __restrict__ mods, const float* __restrict__ nw,
    u16* __restrict__ x1, u16* __restrict__ x2) {
  int row = blockIdx.x * 4 + (threadIdx.x >> 6);  // 0..65535
  int t = threadIdx.x & 63;
  int bt = row >> 15, s = row & 32767;
  int i1 = s >> 12, p1 = (s >> 10) & 3, i2 = (s >> 7) & 7,
      p2 = (s >> 5) & 3, i3 = (s >> 2) & 7, p3 = s & 3;
  int blk = (((i1 << 3) | i2) << 3) | i3;
  int m = selmap[(bt << 9) | blk];
  int d0 = t * 8;
  const float* src = x + (size_t)row * 512 + d0;
  float4 a = *(const float4*)src;
  float4 b = *(const float4*)(src + 4);
  float v[8] = {a.x, a.y, a.z, a.w, b.x, b.y, b.z, b.w};
  const float* mb = mods + bt * 3072;
  if (m >= 0) {
    int p = (p1 << 4) | (p2 << 2) | p3;
    const float* op = opout + ((size_t)m * 64 + p) * 512 + d0;
    float4 oa = *(const float4*)op;
    float4 ob = *(const float4*)(op + 4);
    float ov[8] = {oa.x, oa.y, oa.z, oa.w, ob.x, ob.y, ob.z, ob.w};
    #pragma unroll
    for (int j = 0; j < 8; ++j) v[j] += mb[1024 + d0 + j] * ov[j];
  }
  u16 o1[8];
  #pragma unroll
  for (int j = 0; j < 8; ++j) o1[j] = f2bf(v[j]);
  *(uint4*)(x1 + (size_t)row * 512 + d0) = *(uint4*)o1;
  float sum = 0.f, sq = 0.f;
  #pragma unroll
  for (int j = 0; j < 8; ++j) { sum += v[j]; sq += v[j] * v[j]; }
  #pragma unroll
  for (int mm = 1; mm < 64; mm <<= 1) {
    sum += __shfl_xor(sum, mm, 64);
    sq  += __shfl_xor(sq, mm, 64);
  }
  float mean = sum * (1.f / 512.f);
  float var = sq * (1.f / 512.f) - mean * mean;
  float rstd = rsqrtf(var + 1e-5f);
  u16 o[8];
  #pragma unroll
  for (int j = 0; j < 8; ++j) {
    int d = d0 + j;
    float xn = (v[j] - mean) * rstd * nw[d];
    o[j] = f2bf(xn * (1.f + mb[2048 + d]) + mb[1536 + d]);
  }
  *(uint4*)(x2 + (size_t)row * 512 + d0) = *(uint4*)o;
}

// ---------------- launcher ----------------

extern "C" void kernel_launch(void* const* d_in, const int* in_sizes, int n_in,
                              void* d_out, int out_size, void* d_ws, size_t ws_size,
                              hipStream_t stream) {
  const float* x    = (const float*)d_in[0];
  const float* c    = (const float*)d_in[1];
  const float* cosq = (const float*)d_in[2];
  const float* sinq = (const float*)d_in[3];
  const float* cosk = (const float*)d_in[4];
  const float* sink = (const float*)d_in[5];
  const int* nzb    = (const int*)d_in[6];
  const int* nbrs   = (const int*)d_in[7];
  const float* norm1_w = (const float*)d_in[11];
  const float* qkv_w   = (const float*)d_in[12];
  const float* out_w   = (const float*)d_in[13];
  const float* norm2_w = (const float*)d_in[14];
  const float* mlp_w1  = (const float*)d_in[15];
  const float* mlp_b1  = (const float*)d_in[16];
  const float* mlp_w2  = (const float*)d_in[17];
  const float* mlp_b2  = (const float*)d_in[18];
  const float* adaln_w = (const float*)d_in[19];
  const float* adaln_b = (const float*)d_in[20];
  const float* kv_e    = (const float*)d_in[21];
  float* outp = (float*)d_out;
  char* ws = (char*)d_ws;

  const size_t MB = 1024ull * 1024ull;
  // lifetime-based region map (~390 MiB):
  u16*   qkvb    = (u16*)(ws + 0);            // [0,96)   dead after ropepack/vtrans
  float* opout   = (float*)(ws + 0);          // [0,64)   outproj -> x1ln2
  u16*   hidden  = (u16*)(ws + 0);            // [0,256)  mlp1 -> mlp2
  u16*   xm      = (u16*)(ws + 96 * MB);      // [96,128) dead after qkv gemm
  u16*   attnout = (u16*)(ws + 96 * MB);      // [96,128) attn -> outproj
  u16*   qb      = (u16*)(ws + 128 * MB);     // [128,160) dead after attn
  u16*   kf      = (u16*)(ws + 160 * MB);     // [160,192) dead after attn
  u16*   vT      = (u16*)(ws + 192 * MB);     // [192,224) dead after attn
  u16*   x1      = (u16*)(ws + 256 * MB);     // [256,320) bf16 residual
  u16*   x2      = (u16*)(ws + 320 * MB);     // [320,384)
  char*  S0      = ws + 384 * MB;
  float* mods    = (float*)(S0);              // 24 KiB
  int*   selmap  = (int*)(S0 + 0x8000);       // 4 KiB
  u16*   kempty  = (u16*)(S0 + 0x10000);      // 64 KiB
  u16*   vTempty = (u16*)(S0 + 0x20000);      // 64 KiB
  u16*   qkvw_bf = (u16*)(S0 + 0x30000);              // 1.5 MiB
  u16*   outw_bf = qkvw_bf + (size_t)1536 * 512;      // 0.5 MiB
  u16*   w1_bf   = outw_bf + (size_t)512 * 512;       // 2 MiB
  u16*   w2_bf   = w1_bf + (size_t)2048 * 512;        // 2 MiB

  // prep
  selmap_k<<<1, 1024, 0, stream>>>(nzb, selmap);
  adaln_k<<<dim3(12, 2), 256, 0, stream>>>(c, adaln_w, adaln_b, mods);
  castw_k<<<768, 256, 0, stream>>>(qkv_w, qkvw_bf, 1536 * 512 / 4);
  castw_k<<<256, 256, 0, stream>>>(out_w, outw_bf, 512 * 512 / 4);
  castw_k<<<1024, 256, 0, stream>>>(mlp_w1, w1_bf, 2048 * 512 / 4);
  castw_k<<<1024, 256, 0, stream>>>(mlp_w2, w2_bf, 512 * 2048 / 4);
  kvempty_k<<<128, 256, 0, stream>>>(kv_e, cosk, sink, kempty, vTempty);

  // LN1 + modulate on selected rows
  ln1_k<<<8192, 256, 0, stream>>>(x, norm1_w, mods, nzb, xm);

  // qkv = xm @ qkv_w^T   (32768 x 1536 x 512)
  gemm256<0><<<768, 512, 0, stream>>>(xm, qkvw_bf, 32768, 1536, 512, qkvb,
                                      nullptr, nullptr, nullptr, 0, 6);
  // rope q/k, pack; transpose v
  ropepack_k<<<16384, 256, 0, stream>>>(qkvb, cosq, sinq, cosk, sink, qb, kf);
  vtrans_k<<<4096, 256, 0, stream>>>(qkvb, vT);

  // attention
  attn_k<<<4096, 256, 0, stream>>>(qb, kf, vT, kempty, vTempty, nbrs, selmap, attnout);

  // out projection (32768 x 512 x 512)
  gemm256<1><<<256, 512, 0, stream>>>(attnout, outw_bf, 32768, 512, 512, opout,
                                      nullptr, nullptr, nullptr, 0, 2);

  // x1 = x + gate_msa*proj (bf16), LN2 + modulate -> x2
  x1ln2_k<<<16384, 256, 0, stream>>>(x, opout, selmap, mods, norm2_w, x1, x2);

  // MLP (65536 x 2048 x 512), (65536 x 512 x 2048)
  gemm256<2><<<2048, 512, 0, stream>>>(x2, w1_bf, 65536, 2048, 512, hidden,
                                       mlp_b1, nullptr, nullptr, 0, 8);
  gemm256<3><<<512, 512, 0, stream>>>(hidden, w2_bf, 65536, 512, 2048, outp,
                                      mlp_b2, x1, mods, 0, 2);
}

// Round 5
// 933.969 us; speedup vs baseline: 1.2203x; 1.0135x over previous
//
#include <hip/hip_runtime.h>
#include <cstdint>
#include <cstddef>

typedef unsigned short u16;
typedef __attribute__((ext_vector_type(8))) __bf16 bf16x8;
typedef __attribute__((ext_vector_type(4))) float f32x4;

typedef __attribute__((address_space(1))) const void GAS;
typedef __attribute__((address_space(3))) void LAS;

__device__ __forceinline__ void gld_lds16(const void* g, void* l) {
  __builtin_amdgcn_global_load_lds((GAS*)g, (LAS*)l, 16, 0, 0);
}

__device__ __forceinline__ u16 f2bf(float f) {
  union { float f; unsigned u; } x; x.f = f;
  unsigned r = x.u + 0x7FFFu + ((x.u >> 16) & 1u);
  return (u16)(r >> 16);
}
__device__ __forceinline__ float bf2f(u16 s) {
  union { unsigned u; float f; } x; x.u = ((unsigned)s) << 16;
  return x.f;
}
__device__ __forceinline__ f32x4 mfma16(bf16x8 a, bf16x8 b, f32x4 c) {
  return __builtin_amdgcn_mfma_f32_16x16x32_bf16(a, b, c, 0, 0, 0);
}

// ---------------- small prep kernels ----------------

__global__ void selmap_k(const int* __restrict__ nzb, int* __restrict__ map) {
  int t = threadIdx.x;            // 1024 threads
  map[t] = -1;
  __syncthreads();
  if (t < 512) map[nzb[t]] = t;
}

__global__ __launch_bounds__(256) void castw_k(const float* __restrict__ in,
                                               u16* __restrict__ out, int n4) {
  int i = blockIdx.x * 256 + threadIdx.x;
  if (i >= n4) return;
  float4 v = ((const float4*)in)[i];
  u16 o[4] = {f2bf(v.x), f2bf(v.y), f2bf(v.z), f2bf(v.w)};
  ((uint2*)out)[i] = *(uint2*)o;
}

__global__ __launch_bounds__(256) void adaln_k(const float* __restrict__ c,
    const float* __restrict__ w, const float* __restrict__ b, float* __restrict__ mods) {
  int j = blockIdx.x * 256 + threadIdx.x;  // 0..3071
  int bt = blockIdx.y;
  const float4* cr = (const float4*)(c + bt * 512);
  const float4* wr = (const float4*)(w + (size_t)j * 512);
  float s = 0.f;
  #pragma unroll 4
  for (int k = 0; k < 128; ++k) {
    float4 a = wr[k], q = cr[k];
    s += a.x * q.x + a.y * q.y + a.z * q.z + a.w * q.w;
  }
  mods[bt * 3072 + j] = s + b[j];
}

// rope the shared empty-block K, copy/transpose empty V
__global__ __launch_bounds__(256) void kvempty_k(const float* __restrict__ kve,
    const float* __restrict__ cT, const float* __restrict__ sT,
    u16* __restrict__ kempty, u16* __restrict__ vTempty) {
  int T = blockIdx.x * 256 + threadIdx.x;  // 32768
  int h = T >> 12, p = (T >> 6) & 63, d = T & 63;
  float kv = kve[p * 1024 + h * 64 + d];
  float pv = kve[p * 1024 + h * 64 + (d ^ 32)];
  float cs = cT[p * 64 + d], sn = sT[p * 64 + d];
  float r = kv * cs + ((d < 32) ? -pv : pv) * sn;
  kempty[(h * 64 + p) * 64 + d] = f2bf(r);
  vTempty[(h * 64 + d) * 64 + p] = f2bf(kve[p * 1024 + 512 + h * 64 + d]);
}

// ---------------- LN1 + modulate + block-gather (selected rows only) ----------------

__global__ __launch_bounds__(256) void ln1_k(const float* __restrict__ x,
    const float* __restrict__ nw, const float* __restrict__ mods,
    const int* __restrict__ nzb, u16* __restrict__ xm) {
  int row = blockIdx.x * 4 + (threadIdx.x >> 6);  // 0..32767 (sel*64 + p)
  int t = threadIdx.x & 63;
  int sel = row >> 6, p = row & 63;
  int g = nzb[sel];
  int bt = g >> 9, blk = g & 511;
  int s = (blk >> 6) * 4096 + (p >> 4) * 1024 + ((blk >> 3) & 7) * 128
        + ((p >> 2) & 3) * 32 + (blk & 7) * 4 + (p & 3);
  const float* src = x + ((size_t)bt * 32768 + s) * 512;
  int d0 = t * 8;
  float4 a = *(const float4*)(src + d0);
  float4 b = *(const float4*)(src + d0 + 4);
  float v[8] = {a.x, a.y, a.z, a.w, b.x, b.y, b.z, b.w};
  float sum = 0.f, sq = 0.f;
  #pragma unroll
  for (int j = 0; j < 8; ++j) { sum += v[j]; sq += v[j] * v[j]; }
  #pragma unroll
  for (int m = 1; m < 64; m <<= 1) {
    sum += __shfl_xor(sum, m, 64);
    sq  += __shfl_xor(sq, m, 64);
  }
  float mean = sum * (1.f / 512.f);
  float var = sq * (1.f / 512.f) - mean * mean;
  float rstd = rsqrtf(var + 1e-5f);
  const float* mb = mods + bt * 3072;
  u16 o[8];
  #pragma unroll
  for (int j = 0; j < 8; ++j) {
    int d = d0 + j;
    float xn = (v[j] - mean) * rstd * nw[d];
    o[j] = f2bf(xn * (1.f + mb[512 + d]) + mb[d]);
  }
  *(uint4*)(xm + (size_t)row * 512 + d0) = *(uint4*)o;
}

// ---------------- 256x256 bf16 GEMM, 8-phase schedule (m201 port) ----------------
// BK=64 split in K-halves of 32. LDS: 8 regions of 16 KiB: [buf][A|B][khalf],
// each 256 rows x 4 chunks(16B), chunk position = j ^ ((row>>1)&3) (pre-swizzled
// global source, linear gld_lds dest). Per phase: ds_read 4-8 frags, stage one
// half-tile, barrier, lgkm0, 16 MFMA, barrier. vmcnt(6) at phases 4 and 8 only.
// EPI: 0 bf16; 1 f32; 2 +bias+gelu bf16; 3 +bias, out = bf2f(x1)+gate*val (f32)

#define STG(BUF, X, KH, KT) do {                                         \
    u16* d_ = L + ((BUF) * 4 + (X) * 2 + (KH)) * 8192;                   \
    gld_lds16(((X) ? gB0 : gA0) + (size_t)(KT) * 64 + (KH) * 32, d_ + dst0); \
    gld_lds16(((X) ? gB1 : gA1) + (size_t)(KT) * 64 + (KH) * 32, d_ + dst1); \
  } while (0)

#define MF4(F, AF)                                                       \
    acc[F][0] = mfma16(AF, bfr0, acc[F][0]);                             \
    acc[F][1] = mfma16(AF, bfr1, acc[F][1]);                             \
    acc[F][2] = mfma16(AF, bfr2, acc[F][2]);                             \
    acc[F][3] = mfma16(AF, bfr3, acc[F][3]);

#define PH(BUF, KH, MH, RDB, STMT, VM) do {                              \
    const u16* pa_ = L + ((BUF) * 4 + (KH)) * 8192 + arow + (MH) * 2048; \
    bf16x8 a0_ = *(const bf16x8*)(pa_);                                  \
    bf16x8 a1_ = *(const bf16x8*)(pa_ + 512);                            \
    bf16x8 a2_ = *(const bf16x8*)(pa_ + 1024);                           \
    bf16x8 a3_ = *(const bf16x8*)(pa_ + 1536);                           \
    if (RDB) {                                                           \
      const u16* pb_ = L + ((BUF) * 4 + 2 + (KH)) * 8192 + brow;         \
      bfr0 = *(const bf16x8*)(pb_);                                      \
      bfr1 = *(const bf16x8*)(pb_ + 512);                                \
      bfr2 = *(const bf16x8*)(pb_ + 1024);                               \
      bfr3 = *(const bf16x8*)(pb_ + 1536);                               \
    }                                                                    \
    STMT;                                                                \
    if (VM) asm volatile("s_waitcnt vmcnt(6)" ::: "memory");             \
    __builtin_amdgcn_sched_barrier(0);                                   \
    __builtin_amdgcn_s_barrier();                                        \
    asm volatile("s_waitcnt lgkmcnt(0)" ::: "memory");                   \
    __builtin_amdgcn_sched_barrier(0);                                   \
    __builtin_amdgcn_s_setprio(1);                                       \
    MF4((MH) * 4 + 0, a0_)                                               \
    MF4((MH) * 4 + 1, a1_)                                               \
    MF4((MH) * 4 + 2, a2_)                                               \
    MF4((MH) * 4 + 3, a3_)                                               \
    __builtin_amdgcn_s_setprio(0);                                       \
    __builtin_amdgcn_sched_barrier(0);                                   \
    __builtin_amdgcn_s_barrier();                                        \
  } while (0)

template <int EPI>
__global__ __launch_bounds__(512, 2) void gemm8p(const u16* __restrict__ A,
    const u16* __restrict__ W, int M, int N, int K, void* __restrict__ outp,
    const float* __restrict__ bias, const u16* __restrict__ x1,
    const float* __restrict__ mods, int rowOff, int NB) {
  __shared__ u16 L[65536];               // 128 KiB, 8 regions x 8192 u16
  const int nwg = gridDim.x;
  const int cpx = nwg >> 3;
  const int tile = ((int)blockIdx.x & 7) * cpx + ((int)blockIdx.x >> 3);
  const int bm = (tile / NB) * 256, bn = (tile % NB) * 256;
  const int tid = threadIdx.x;
  const int w = tid >> 6, l = tid & 63, lr = l & 15, lg = l >> 4;
  const int wr = w >> 2, wc = w & 3;

  // stage source pointers (pre-swizzled): slot s -> row s>>2, pos s&3,
  // global chunk j = pos ^ ((row>>1)&3)
  const int r0 = tid >> 2, j0 = (tid & 3) ^ ((r0 >> 1) & 3);
  const int s1 = 512 + tid;
  const int r1 = s1 >> 2, j1 = (s1 & 3) ^ ((r1 >> 1) & 3);
  const u16* gA0 = A + (size_t)(bm + r0) * K + j0 * 8;
  const u16* gA1 = A + (size_t)(bm + r1) * K + j1 * 8;
  const u16* gB0 = W + (size_t)(bn + r0) * K + j0 * 8;
  const u16* gB1 = W + (size_t)(bn + r1) * K + j1 * 8;
  const int dst0 = tid * 8, dst1 = (512 + tid) * 8;

  // frag read offsets (u16 units within a region)
  const int cswz8 = ((lg ^ ((lr >> 1) & 3)) << 3);
  const int arow = (wr * 128 + lr) * 32 + cswz8;
  const int brow = (wc * 64 + lr) * 32 + cswz8;

  f32x4 acc[8][4];
  #pragma unroll
  for (int i = 0; i < 8; ++i)
    #pragma unroll
    for (int j = 0; j < 4; ++j) acc[i][j] = (f32x4){0.f, 0.f, 0.f, 0.f};
  bf16x8 bfr0, bfr1, bfr2, bfr3;

  const int NT = K >> 6;                 // 64-wide K-tiles (even)
  // prologue: tile0 fully (first 4 halves issued), tile1 minus A.k1
  STG(0, 1, 0, 0); STG(0, 0, 0, 0); STG(0, 1, 1, 0); STG(0, 0, 1, 0);
  STG(1, 1, 0, 1); STG(1, 0, 0, 1); STG(1, 1, 1, 1);
  asm volatile("s_waitcnt vmcnt(6)" ::: "memory");
  __builtin_amdgcn_s_barrier();

  const int NIT = NT >> 1;
  for (int I = 0; I < NIT; ++I) {
    const int t1 = 2 * I + 1, t2k = 2 * I + 2, t3k = 2 * I + 3;
    const bool t2v = t2k < NT, t3v = t3k < NT;
    PH(0, 0, 0, 1, STG(1, 0, 1, t1), 0);           // P1 + stage A.k1(t1)->buf1
    PH(0, 0, 1, 0, if (t2v) STG(0, 1, 0, t2k), 0); // P2 + B.k0(t2)->buf0
    PH(0, 1, 0, 1, if (t2v) STG(0, 0, 0, t2k), 0); // P3 + A.k0(t2)
    PH(0, 1, 1, 0, if (t2v) STG(0, 1, 1, t2k), 1); // P4 + B.k1(t2), vmcnt(6)
    PH(1, 0, 0, 1, if (t2v) STG(0, 0, 1, t2k), 0); // P5 + A.k1(t2)
    PH(1, 0, 1, 0, if (t3v) STG(1, 1, 0, t3k), 0); // P6 + B.k0(t3)->buf1
    PH(1, 1, 0, 1, if (t3v) STG(1, 0, 0, t3k), 0); // P7 + A.k0(t3)
    PH(1, 1, 1, 0, if (t3v) STG(1, 1, 1, t3k), 1); // P8 + B.k1(t3), vmcnt(6)
  }

  const int row0 = bm + wr * 128, col0 = bn + wc * 64;
  #pragma unroll
  for (int mf = 0; mf < 8; ++mf) {
    #pragma unroll
    for (int nf = 0; nf < 4; ++nf) {
      #pragma unroll
      for (int j = 0; j < 4; ++j) {
        int row = row0 + mf * 16 + lg * 4 + j;
        int col = col0 + nf * 16 + lr;
        float v = acc[mf][nf][j];
        if constexpr (EPI == 0) {
          ((u16*)outp)[(size_t)row * N + col] = f2bf(v);
        } else if constexpr (EPI == 1) {
          ((float*)outp)[(size_t)row * N + col] = v;
        } else if constexpr (EPI == 2) {
          v += bias[col];
          float z = 1.5957691216057308f * (v + 0.044715f * v * v * v);
          float t = 1.f - 2.f / (1.f + __expf(z));   // tanh(z/2) safe at +-inf
          ((u16*)outp)[(size_t)row * N + col] = f2bf(0.5f * v * (1.f + t));
        } else {
          v += bias[col];
          int grow = rowOff + row;
          int bt = grow >> 15;
          float gate = mods[bt * 3072 + 2560 + col];
          ((float*)outp)[(size_t)grow * 512 + col] =
              bf2f(x1[(size_t)grow * 512 + col]) + gate * v;
        }
      }
    }
  }
}

// ---------------- rope + pack q/k into [sel][h][p][d] ----------------

__global__ __launch_bounds__(256) void ropepack_k(const u16* __restrict__ qkv,
    const float* __restrict__ cq, const float* __restrict__ sq,
    const float* __restrict__ ck, const float* __restrict__ sk,
    u16* __restrict__ qb, u16* __restrict__ kb) {
  int T = blockIdx.x * 256 + threadIdx.x;  // 32768 * 128
  int row = T >> 7, oct = T & 127;
  int c0 = oct * 8;
  int sel = row >> 6, p = row & 63;
  int isk = (c0 >= 512);
  int chn = c0 & 511;
  int h = chn >> 6, d0 = chn & 63;
  int lower = (d0 < 32);
  const u16* base = qkv + (size_t)row * 1536 + (isk ? 512 : 0) + h * 64;
  u16 vm[8], vp[8];
  *(uint4*)vm = *(const uint4*)(base + d0);
  *(uint4*)vp = *(const uint4*)(base + (d0 ^ 32));
  const float* cT = (isk ? ck : cq) + p * 64 + d0;
  const float* sT = (isk ? sk : sq) + p * 64 + d0;
  float scale = isk ? 1.f : 0.125f;  // fold 1/sqrt(dh) into q
  u16 o[8];
  #pragma unroll
  for (int j = 0; j < 8; ++j) {
    float a = bf2f(vm[j]), b = bf2f(vp[j]);
    float r = a * cT[j] + (lower ? -b : b) * sT[j];
    o[j] = f2bf(r * scale);
  }
  u16* dst = (isk ? kb : qb) + (((size_t)sel * 8 + h) * 64 + p) * 64 + d0;
  *(uint4*)dst = *(uint4*)o;
}

// ---------------- v transpose: qkv v-part -> vT [sel][h][d][p] ----------------

__global__ __launch_bounds__(256) void vtrans_k(const u16* __restrict__ qkv,
                                                u16* __restrict__ vT) {
  __shared__ u16 tb[64 * 65];
  int sel = blockIdx.x >> 3, h = blockIdx.x & 7;
  int tid = threadIdx.x;
  int p = tid >> 2, q16 = (tid & 3) * 16;
  const u16* src = qkv + (size_t)(sel * 64 + p) * 1536 + 1024 + h * 64 + q16;
  u16 ld[16];
  *(uint4*)&ld[0] = *(const uint4*)src;
  *(uint4*)&ld[8] = *(const uint4*)(src + 8);
  #pragma unroll
  for (int j = 0; j < 16; ++j) tb[p * 65 + q16 + j] = ld[j];
  __syncthreads();
  int d = tid >> 2, po = (tid & 3) * 16;
  u16 o[16];
  #pragma unroll
  for (int j = 0; j < 16; ++j) o[j] = tb[(po + j) * 65 + d];
  u16* dst = vT + (((size_t)sel * 8 + h) * 64 + d) * 64 + po;
  *(uint4*)dst = *(uint4*)&o[0];
  *(uint4*)(dst + 8) = *(uint4*)&o[8];
}

// ---------------- attention: flash-style over neighbors ----------------

__global__ __launch_bounds__(256, 4) void attn_k(const u16* __restrict__ qbuf,
    const u16* __restrict__ kfull, const u16* __restrict__ vT,
    const u16* __restrict__ kempty, const u16* __restrict__ vTempty,
    const int* __restrict__ nbrs, const int* __restrict__ selmap,
    u16* __restrict__ attnout) {
  __shared__ u16 KB[2][4096];        // 16 KiB, K tile [64 k][64 d], chunk^=(row&7)
  __shared__ u16 Pl[4][16][72];      // 9.2 KiB, per-wave P
  int bid = blockIdx.x;
  int swz = (bid & 7) * 512 + (bid >> 3);   // XCD-chunked (4096 % 8 == 0, bijective)
  int sel = swz >> 3, h = swz & 7;
  int tid = threadIdx.x;
  int w = tid >> 6, l = tid & 63, lr = l & 15, lg = l >> 4;

  int mmv[7];
  #pragma unroll
  for (int n = 0; n < 7; ++n) mmv[n] = selmap[nbrs[sel * 7 + n]];

  const u16* qg = qbuf + (((size_t)sel * 8 + h) * 64 + w * 16) * 64;
  bf16x8 qf0 = *(const bf16x8*)(qg + lr * 64 + lg * 8);
  bf16x8 qf1 = *(const bf16x8*)(qg + lr * 64 + 32 + lg * 8);

  // staging: LDS slot s = i*256+tid holds K[row=s>>3][chunk=(s&7)^(row&7)]
  int srow = tid >> 3;
  int soff = srow * 64 + (((tid & 7) ^ (srow & 7)) << 3);  // u16 units; i=1: +2048
  size_t hoff = (size_t)h * 4096;

  {
    const u16* kp = (mmv[0] >= 0) ? kfull + (size_t)mmv[0] * 32768 + hoff
                                  : kempty + hoff;
    gld_lds16(kp + soff, &KB[0][w * 512]);
    gld_lds16(kp + soff + 2048, &KB[0][2048 + w * 512]);
  }

  f32x4 o[4];
  float mrun[4], lrun[4];
  #pragma unroll
  for (int ct = 0; ct < 4; ++ct) o[ct] = (f32x4){0.f, 0.f, 0.f, 0.f};
  #pragma unroll
  for (int r = 0; r < 4; ++r) { mrun[r] = -1e30f; lrun[r] = 0.f; }

  #pragma unroll
  for (int n = 0; n < 7; ++n) {
    if (n < 6) {
      const u16* kp = (mmv[n + 1] >= 0) ? kfull + (size_t)mmv[n + 1] * 32768 + hoff
                                        : kempty + hoff;
      int b = (n + 1) & 1;
      gld_lds16(kp + soff, &KB[b][w * 512]);
      gld_lds16(kp + soff + 2048, &KB[b][2048 + w * 512]);
      asm volatile("s_waitcnt vmcnt(2)" ::: "memory");
    } else {
      asm volatile("s_waitcnt vmcnt(0)" ::: "memory");
    }
    __builtin_amdgcn_s_barrier();
    __builtin_amdgcn_sched_barrier(0);

    const u16* kl = &KB[n & 1][0];
    const u16* vp = (mmv[n] >= 0) ? vT + (size_t)mmv[n] * 32768 + hoff
                                  : vTempty + hoff;
    // QK^T for this neighbor
    f32x4 s4[4];
    int xr = lr & 7;
    #pragma unroll
    for (int ct = 0; ct < 4; ++ct) {
      int row = ct * 16 + lr;
      bf16x8 b0 = *(const bf16x8*)(kl + row * 64 + ((lg ^ xr) << 3));
      bf16x8 b1 = *(const bf16x8*)(kl + row * 64 + (((lg + 4) ^ xr) << 3));
      f32x4 z = (f32x4){0.f, 0.f, 0.f, 0.f};
      z = mfma16(qf0, b0, z);
      z = mfma16(qf1, b1, z);
      s4[ct] = z;
    }
    // online softmax update
    float rmax[4], sc[4], rs[4];
    #pragma unroll
    for (int r = 0; r < 4; ++r)
      rmax[r] = fmaxf(fmaxf(s4[0][r], s4[1][r]), fmaxf(s4[2][r], s4[3][r]));
    #pragma unroll
    for (int r = 0; r < 4; ++r) {
      #pragma unroll
      for (int ms = 1; ms < 16; ms <<= 1)
        rmax[r] = fmaxf(rmax[r], __shfl_xor(rmax[r], ms, 64));
      float mn = fmaxf(mrun[r], rmax[r]);
      sc[r] = __expf(mrun[r] - mn);
      mrun[r] = mn;
      rs[r] = 0.f;
    }
    #pragma unroll
    for (int ct = 0; ct < 4; ++ct)
      #pragma unroll
      for (int r = 0; r < 4; ++r) {
        float e = __expf(s4[ct][r] - mrun[r]);
        s4[ct][r] = e;
        rs[r] += e;
      }
    #pragma unroll
    for (int r = 0; r < 4; ++r) {
      #pragma unroll
      for (int ms = 1; ms < 16; ms <<= 1) rs[r] += __shfl_xor(rs[r], ms, 64);
      lrun[r] = lrun[r] * sc[r] + rs[r];
    }
    #pragma unroll
    for (int ct = 0; ct < 4; ++ct)
      #pragma unroll
      for (int r = 0; r < 4; ++r) o[ct][r] *= sc[r];
    // P -> LDS (wave-local), then PV with direct-global V
    #pragma unroll
    for (int ct = 0; ct < 4; ++ct)
      #pragma unroll
      for (int r = 0; r < 4; ++r)
        Pl[w][lg * 4 + r][ct * 16 + lr] = f2bf(s4[ct][r]);
    asm volatile("s_waitcnt lgkmcnt(0)" ::: "memory");
    __builtin_amdgcn_sched_barrier(0);
    bf16x8 pa0 = *(const bf16x8*)&Pl[w][lr][lg * 8];
    bf16x8 pa1 = *(const bf16x8*)&Pl[w][lr][32 + lg * 8];
    #pragma unroll
    for (int ct = 0; ct < 4; ++ct) {
      bf16x8 v0 = *(const bf16x8*)(vp + (ct * 16 + lr) * 64 + lg * 8);
      bf16x8 v1 = *(const bf16x8*)(vp + (ct * 16 + lr) * 64 + 32 + lg * 8);
      o[ct] = mfma16(pa0, v0, o[ct]);
      o[ct] = mfma16(pa1, v1, o[ct]);
    }
    asm volatile("" ::: "memory");
    __builtin_amdgcn_s_barrier();     // KB[n&1] free for restage at iter n+1
    __builtin_amdgcn_sched_barrier(0);
  }

  float inv[4];
  #pragma unroll
  for (int r = 0; r < 4; ++r) inv[r] = 1.f / lrun[r];
  #pragma unroll
  for (int ct = 0; ct < 4; ++ct)
    #pragma unroll
    for (int r = 0; r < 4; ++r) {
      int p = w * 16 + lg * 4 + r;
      int d = ct * 16 + lr;
      attnout[((size_t)sel * 64 + p) * 512 + h * 64 + d] = f2bf(o[ct][r] * inv[r]);
    }
}

// ---------------- x1 = x + gate*proj (bf16), then LN2 + modulate -> x2 ----------------

__global__ __launch_bounds__(256) void x1ln2_k(const float* __restrict__ x,
    const float* __restrict__ opout, const int* __restrict__ selmap,
    const float* __restrict__ mods, const float* __restrict__ nw,
    u16* __restrict__ x1, u16* __restrict__ x2) {
  int row = blockIdx.x * 4 + (threadIdx.x >> 6);  // 0..65535
  int t = threadIdx.x & 63;
  int bt = row >> 15, s = row & 32767;
  int i1 = s >> 12, p1 = (s >> 10) & 3, i2 = (s >> 7) & 7,
      p2 = (s >> 5) & 3, i3 = (s >> 2) & 7, p3 = s & 3;
  int blk = (((i1 << 3) | i2) << 3) | i3;
  int m = selmap[(bt << 9) | blk];
  int d0 = t * 8;
  const float* src = x + (size_t)row * 512 + d0;
  float4 a = *(const float4*)src;
  float4 b = *(const float4*)(src + 4);
  float v[8] = {a.x, a.y, a.z, a.w, b.x, b.y, b.z, b.w};
  const float* mb = mods + bt * 3072;
  if (m >= 0) {
    int p = (p1 << 4) | (p2 << 2) | p3;
    const float* op = opout + ((size_t)m * 64 + p) * 512 + d0;
    float4 oa = *(const float4*)op;
    float4 ob = *(const float4*)(op + 4);
    float ov[8] = {oa.x, oa.y, oa.z, oa.w, ob.x, ob.y, ob.z, ob.w};
    #pragma unroll
    for (int j = 0; j < 8; ++j) v[j] += mb[1024 + d0 + j] * ov[j];
  }
  u16 o1[8];
  #pragma unroll
  for (int j = 0; j < 8; ++j) o1[j] = f2bf(v[j]);
  *(uint4*)(x1 + (size_t)row * 512 + d0) = *(uint4*)o1;
  float sum = 0.f, sq = 0.f;
  #pragma unroll
  for (int j = 0; j < 8; ++j) { sum += v[j]; sq += v[j] * v[j]; }
  #pragma unroll
  for (int mm = 1; mm < 64; mm <<= 1) {
    sum += __shfl_xor(sum, mm, 64);
    sq  += __shfl_xor(sq, mm, 64);
  }
  float mean = sum * (1.f / 512.f);
  float var = sq * (1.f / 512.f) - mean * mean;
  float rstd = rsqrtf(var + 1e-5f);
  u16 o[8];
  #pragma unroll
  for (int j = 0; j < 8; ++j) {
    int d = d0 + j;
    float xn = (v[j] - mean) * rstd * nw[d];
    o[j] = f2bf(xn * (1.f + mb[2048 + d]) + mb[1536 + d]);
  }
  *(uint4*)(x2 + (size_t)row * 512 + d0) = *(uint4*)o;
}

// ---------------- launcher ----------------

extern "C" void kernel_launch(void* const* d_in, const int* in_sizes, int n_in,
                              void* d_out, int out_size, void* d_ws, size_t ws_size,
                              hipStream_t stream) {
  const float* x    = (const float*)d_in[0];
  const float* c    = (const float*)d_in[1];
  const float* cosq = (const float*)d_in[2];
  const float* sinq = (const float*)d_in[3];
  const float* cosk = (const float*)d_in[4];
  const float* sink = (const float*)d_in[5];
  const int* nzb    = (const int*)d_in[6];
  const int* nbrs   = (const int*)d_in[7];
  const float* norm1_w = (const float*)d_in[11];
  const float* qkv_w   = (const float*)d_in[12];
  const float* out_w   = (const float*)d_in[13];
  const float* norm2_w = (const float*)d_in[14];
  const float* mlp_w1  = (const float*)d_in[15];
  const float* mlp_b1  = (const float*)d_in[16];
  const float* mlp_w2  = (const float*)d_in[17];
  const float* mlp_b2  = (const float*)d_in[18];
  const float* adaln_w = (const float*)d_in[19];
  const float* adaln_b = (const float*)d_in[20];
  const float* kv_e    = (const float*)d_in[21];
  float* outp = (float*)d_out;
  char* ws = (char*)d_ws;

  const size_t MB = 1024ull * 1024ull;
  // lifetime-based region map (~390 MiB):
  u16*   qkvb    = (u16*)(ws + 0);            // [0,96)   dead after ropepack/vtrans
  float* opout   = (float*)(ws + 0);          // [0,64)   outproj -> x1ln2
  u16*   hidden  = (u16*)(ws + 0);            // [0,256)  mlp1 -> mlp2
  u16*   xm      = (u16*)(ws + 96 * MB);      // [96,128) dead after qkv gemm
  u16*   attnout = (u16*)(ws + 96 * MB);      // [96,128) attn -> outproj
  u16*   qb      = (u16*)(ws + 128 * MB);     // [128,160) dead after attn
  u16*   kf      = (u16*)(ws + 160 * MB);     // [160,192) dead after attn
  u16*   vT      = (u16*)(ws + 192 * MB);     // [192,224) dead after attn
  u16*   x1      = (u16*)(ws + 256 * MB);     // [256,320) bf16 residual
  u16*   x2      = (u16*)(ws + 320 * MB);     // [320,384)
  char*  S0      = ws + 384 * MB;
  float* mods    = (float*)(S0);              // 24 KiB
  int*   selmap  = (int*)(S0 + 0x8000);       // 4 KiB
  u16*   kempty  = (u16*)(S0 + 0x10000);      // 64 KiB
  u16*   vTempty = (u16*)(S0 + 0x20000);      // 64 KiB
  u16*   qkvw_bf = (u16*)(S0 + 0x30000);              // 1.5 MiB
  u16*   outw_bf = qkvw_bf + (size_t)1536 * 512;      // 0.5 MiB
  u16*   w1_bf   = outw_bf + (size_t)512 * 512;       // 2 MiB
  u16*   w2_bf   = w1_bf + (size_t)2048 * 512;        // 2 MiB

  // prep
  selmap_k<<<1, 1024, 0, stream>>>(nzb, selmap);
  adaln_k<<<dim3(12, 2), 256, 0, stream>>>(c, adaln_w, adaln_b, mods);
  castw_k<<<768, 256, 0, stream>>>(qkv_w, qkvw_bf, 1536 * 512 / 4);
  castw_k<<<256, 256, 0, stream>>>(out_w, outw_bf, 512 * 512 / 4);
  castw_k<<<1024, 256, 0, stream>>>(mlp_w1, w1_bf, 2048 * 512 / 4);
  castw_k<<<1024, 256, 0, stream>>>(mlp_w2, w2_bf, 512 * 2048 / 4);
  kvempty_k<<<128, 256, 0, stream>>>(kv_e, cosk, sink, kempty, vTempty);

  // LN1 + modulate on selected rows
  ln1_k<<<8192, 256, 0, stream>>>(x, norm1_w, mods, nzb, xm);

  // qkv = xm @ qkv_w^T   (32768 x 1536 x 512)
  gemm8p<0><<<768, 512, 0, stream>>>(xm, qkvw_bf, 32768, 1536, 512, qkvb,
                                     nullptr, nullptr, nullptr, 0, 6);
  // rope q/k, pack; transpose v
  ropepack_k<<<16384, 256, 0, stream>>>(qkvb, cosq, sinq, cosk, sink, qb, kf);
  vtrans_k<<<4096, 256, 0, stream>>>(qkvb, vT);

  // attention
  attn_k<<<4096, 256, 0, stream>>>(qb, kf, vT, kempty, vTempty, nbrs, selmap, attnout);

  // out projection (32768 x 512 x 512)
  gemm8p<1><<<256, 512, 0, stream>>>(attnout, outw_bf, 32768, 512, 512, opout,
                                     nullptr, nullptr, nullptr, 0, 2);

  // x1 = x + gate_msa*proj (bf16), LN2 + modulate -> x2
  x1ln2_k<<<16384, 256, 0, stream>>>(x, opout, selmap, mods, norm2_w, x1, x2);

  // MLP (65536 x 2048 x 512), (65536 x 512 x 2048)
  gemm8p<2><<<2048, 512, 0, stream>>>(x2, w1_bf, 65536, 2048, 512, hidden,
                                      mlp_b1, nullptr, nullptr, 0, 8);
  gemm8p<3><<<512, 512, 0, stream>>>(hidden, w2_bf, 65536, 512, 2048, outp,
                                     mlp_b2, x1, mods, 0, 2);
}